// Round 1
// baseline (855.289 us; speedup 1.0000x reference)
//
#include <hip/hip_runtime.h>
#include <hip/hip_bf16.h>
#include <math.h>

#define B_SZ 2048
#define L_SEQ 8
#define DMODEL 128
#define DSTATE 64
#define HEADDIM 32
#define DCONV 4
#define DINNER 256
#define NHEADS 8
#define DCONVCH 384   // DINNER + 2*DSTATE
#define DINPROJ 648   // 2*DINNER + 2*DSTATE + NHEADS

__device__ __forceinline__ float siluf(float x) {
    return x / (1.f + expf(-x));
}

// ---------------------------------------------------------------------------
// Mamba2 block: one workgroup per batch element. Everything staged in LDS.
// Scan is computed in closed (quadratic SSD) form since L=8:
//   y_t[h,p] = sum_{s<=t} G[t,s] * exp(A_h*(cum_t-cum_s)) * dt_s * x_s[h,p]
//              + D_h * x_t[h,p],   G[t,s] = B_s . C_t
// ---------------------------------------------------------------------------
__global__ __launch_bounds__(256) void mamba_kernel(
    const float* __restrict__ u,      // (B, 8, 128)
    const float* __restrict__ Win,    // (128, 648)
    const float* __restrict__ convw,  // (4, 384)
    const float* __restrict__ convb,  // (384)
    const float* __restrict__ dtb,    // (8)
    const float* __restrict__ Alog,   // (8)
    const float* __restrict__ Dp,     // (8)
    const float* __restrict__ normw,  // (256)
    const float* __restrict__ Wout,   // (256, 128)
    float* __restrict__ outf)         // (B, 8, 128)
{
    const int b = blockIdx.x;
    const int tid = threadIdx.x;

    __shared__ float u_s[L_SEQ * DMODEL];        // 1024
    __shared__ float zx[L_SEQ * DINPROJ];        // 5184: z | xBC_raw | dt
    __shared__ float xBC[L_SEQ * DCONVCH];       // 3072: post conv+silu
    __shared__ float dtv[L_SEQ][NHEADS];
    __shared__ float cum[L_SEQ][NHEADS];
    __shared__ float Gm[L_SEQ][L_SEQ];           // [t][s]
    __shared__ float coef[L_SEQ][L_SEQ][NHEADS]; // 512
    __shared__ float y[L_SEQ * DINNER];          // 2048
    __shared__ float red[L_SEQ][32];
    __shared__ float rstd[L_SEQ];

    // 1. load u rows for this batch
    for (int i = tid; i < L_SEQ * DMODEL; i += 256)
        u_s[i] = u[b * (L_SEQ * DMODEL) + i];
    __syncthreads();

    // 2. in_proj: zx[l][j] = sum_k u_s[l][k] * Win[k][j]
    for (int j = tid; j < DINPROJ; j += 256) {
        float acc[L_SEQ];
        #pragma unroll
        for (int l = 0; l < L_SEQ; ++l) acc[l] = 0.f;
        for (int k = 0; k < DMODEL; ++k) {
            float w = Win[k * DINPROJ + j];
            #pragma unroll
            for (int l = 0; l < L_SEQ; ++l)
                acc[l] += u_s[l * DMODEL + k] * w;
        }
        #pragma unroll
        for (int l = 0; l < L_SEQ; ++l) zx[l * DINPROJ + j] = acc[l];
    }
    __syncthreads();

    // 3. depthwise causal conv1d + SiLU over channels 256..639
    for (int i = tid; i < L_SEQ * DCONVCH; i += 256) {
        int l = i / DCONVCH, c = i % DCONVCH;
        float s = convb[c];
        #pragma unroll
        for (int k = 0; k < DCONV; ++k) {
            int lp = l + k - (DCONV - 1);
            if (lp >= 0) s += zx[lp * DINPROJ + DINNER + c] * convw[k * DCONVCH + c];
        }
        xBC[i] = siluf(s);
    }
    // 4. dt = softplus(dt_raw + dtb)
    if (tid < L_SEQ * NHEADS) {
        int l = tid / NHEADS, h = tid % NHEADS;
        float v = zx[l * DINPROJ + 2 * DINNER + 2 * DSTATE + h] + dtb[h];
        dtv[l][h] = (v > 20.f) ? v : log1pf(expf(v));
    }
    __syncthreads();
    // cumsum of dt per head
    if (tid < NHEADS) {
        float c = 0.f;
        for (int l = 0; l < L_SEQ; ++l) { c += dtv[l][tid]; cum[l][tid] = c; }
    }
    // 5. G[t][s] = B_s . C_t  (B at xBC cols 256..319, C at 320..383)
    if (tid >= 64 && tid < 128) {
        int i = tid - 64;
        int t = i / L_SEQ, s = i % L_SEQ;
        float acc = 0.f;
        for (int n = 0; n < DSTATE; ++n)
            acc += xBC[s * DCONVCH + DINNER + n] * xBC[t * DCONVCH + DINNER + DSTATE + n];
        Gm[t][s] = acc;
    }
    __syncthreads();
    // 5b. coef[t][s][h]
    for (int i = tid; i < L_SEQ * L_SEQ * NHEADS; i += 256) {
        int t = i / (L_SEQ * NHEADS), s = (i / NHEADS) % L_SEQ, h = i % NHEADS;
        float A = -expf(Alog[h]);
        coef[t][s][h] = (s <= t)
            ? Gm[t][s] * expf(A * (cum[t][h] - cum[s][h])) * dtv[s][h]
            : 0.f;
    }
    __syncthreads();
    // 6. y[t, c] (c = h*32+p)
    for (int i = tid; i < L_SEQ * DINNER; i += 256) {
        int t = i / DINNER, c = i % DINNER;
        int h = c / HEADDIM;
        float acc = Dp[h] * xBC[t * DCONVCH + c];
        for (int s = 0; s <= t; ++s)
            acc += coef[t][s][h] * xBC[s * DCONVCH + c];
        y[i] = acc;
    }
    __syncthreads();
    // 7. gate with silu(z), then RMSNorm * normw
    for (int i = tid; i < L_SEQ * DINNER; i += 256) {
        int l = i / DINNER, c = i % DINNER;
        float zv = zx[l * DINPROJ + c];
        y[i] = y[i] * siluf(zv);
    }
    __syncthreads();
    {
        int l = tid / 32, j = tid % 32;
        float p = 0.f;
        #pragma unroll
        for (int c = j * 8; c < j * 8 + 8; ++c) {
            float v = y[l * DINNER + c];
            p += v * v;
        }
        red[l][j] = p;
    }
    __syncthreads();
    if (tid < L_SEQ) {
        float s = 0.f;
        for (int j = 0; j < 32; ++j) s += red[tid][j];
        rstd[tid] = rsqrtf(s / (float)DINNER + 1e-5f);
    }
    __syncthreads();
    for (int i = tid; i < L_SEQ * DINNER; i += 256) {
        int l = i / DINNER, c = i % DINNER;
        y[i] = y[i] * rstd[l] * normw[c];
    }
    __syncthreads();
    // 8. out_proj: outf[b,l,m] = sum_c y[l,c] * Wout[c,m]
    if (tid < DMODEL) {
        int m = tid;
        float acc[L_SEQ];
        #pragma unroll
        for (int l = 0; l < L_SEQ; ++l) acc[l] = 0.f;
        for (int c = 0; c < DINNER; ++c) {
            float w = Wout[c * DMODEL + m];
            #pragma unroll
            for (int l = 0; l < L_SEQ; ++l)
                acc[l] += y[l * DINNER + c] * w;
        }
        #pragma unroll
        for (int l = 0; l < L_SEQ; ++l)
            outf[(b * L_SEQ + l) * DMODEL + m] = acc[l];
    }
}

// ---------------------------------------------------------------------------
// Both cross-attentions: one workgroup per batch element.
// pass 0: st_a = attn(Q=st_f, KV=exp_f; cs_*)  -> x[..., 0:128]
// pass 1: exp_a = attn(Q=exp_f, KV=st_f; cx_*) -> x[..., 128:256]
// ---------------------------------------------------------------------------
__global__ __launch_bounds__(256) void attn_kernel(
    const float* __restrict__ st_f,   // (B,8,128)
    const float* __restrict__ exp_f,  // (B,8,128)
    const float* __restrict__ cs_Wq, const float* __restrict__ cs_bq,
    const float* __restrict__ cs_Wk, const float* __restrict__ cs_bk,
    const float* __restrict__ cs_Wv, const float* __restrict__ cs_bv,
    const float* __restrict__ cs_Wo, const float* __restrict__ cs_bo,
    const float* __restrict__ cx_Wq, const float* __restrict__ cx_bq,
    const float* __restrict__ cx_Wk, const float* __restrict__ cx_bk,
    const float* __restrict__ cx_Wv, const float* __restrict__ cx_bv,
    const float* __restrict__ cx_Wo, const float* __restrict__ cx_bo,
    float* __restrict__ x)            // (B, 2048)
{
    const int b = blockIdx.x;
    const int tid = threadIdx.x;
    const float scale = 0.08838834764831845f; // 128^-0.5

    __shared__ float stf[L_SEQ * DMODEL];
    __shared__ float exf[L_SEQ * DMODEL];
    __shared__ float Q[L_SEQ * DMODEL];
    __shared__ float K[L_SEQ * DMODEL];
    __shared__ float V[L_SEQ * DMODEL];
    __shared__ float att[L_SEQ][L_SEQ];
    __shared__ float attv[L_SEQ * DMODEL];

    for (int i = tid; i < L_SEQ * DMODEL; i += 256) {
        stf[i] = st_f[b * (L_SEQ * DMODEL) + i];
        exf[i] = exp_f[b * (L_SEQ * DMODEL) + i];
    }
    __syncthreads();

    const int m = tid & 127;   // column, fixed per thread
    const int l0 = tid >> 7;   // 0 or 1; rows l0, l0+2, l0+4, l0+6

    for (int pass = 0; pass < 2; ++pass) {
        const float* qsrc = pass ? exf : stf;
        const float* kvsrc = pass ? stf : exf;
        const float* Wq = pass ? cx_Wq : cs_Wq;  const float* bq = pass ? cx_bq : cs_bq;
        const float* Wk = pass ? cx_Wk : cs_Wk;  const float* bk = pass ? cx_bk : cs_bk;
        const float* Wv = pass ? cx_Wv : cs_Wv;  const float* bv = pass ? cx_bv : cs_bv;
        const float* Wo = pass ? cx_Wo : cs_Wo;  const float* bo = pass ? cx_bo : cs_bo;
        const int off = pass ? DMODEL : 0;

        // Q / K / V projections (each thread: 4 rows, same column m)
        {
            float aq[4], ak[4], av[4];
            float bqv = bq[m], bkv = bk[m], bvv = bv[m];
            #pragma unroll
            for (int j = 0; j < 4; ++j) { aq[j] = bqv; ak[j] = bkv; av[j] = bvv; }
            for (int k = 0; k < DMODEL; ++k) {
                float wq = Wq[k * DMODEL + m];
                float wk = Wk[k * DMODEL + m];
                float wv = Wv[k * DMODEL + m];
                #pragma unroll
                for (int j = 0; j < 4; ++j) {
                    int l = l0 + 2 * j;
                    float qv = qsrc[l * DMODEL + k];
                    float kv = kvsrc[l * DMODEL + k];
                    aq[j] += qv * wq;
                    ak[j] += kv * wk;
                    av[j] += kv * wv;
                }
            }
            #pragma unroll
            for (int j = 0; j < 4; ++j) {
                int l = l0 + 2 * j;
                Q[l * DMODEL + m] = aq[j];
                K[l * DMODEL + m] = ak[j];
                V[l * DMODEL + m] = av[j];
            }
        }
        __syncthreads();

        // scores
        if (tid < 64) {
            int q = tid / L_SEQ, k = tid % L_SEQ;
            float s = 0.f;
            for (int d = 0; d < DMODEL; ++d)
                s += Q[q * DMODEL + d] * K[k * DMODEL + d];
            att[q][k] = s * scale;
        }
        __syncthreads();
        // softmax per row
        if (tid < L_SEQ) {
            int q = tid;
            float mx = -1e30f;
            #pragma unroll
            for (int k = 0; k < L_SEQ; ++k) mx = fmaxf(mx, att[q][k]);
            float sum = 0.f;
            #pragma unroll
            for (int k = 0; k < L_SEQ; ++k) {
                float e = expf(att[q][k] - mx);
                att[q][k] = e;
                sum += e;
            }
            float inv = 1.f / sum;
            #pragma unroll
            for (int k = 0; k < L_SEQ; ++k) att[q][k] *= inv;
        }
        __syncthreads();
        // att @ V
        {
            #pragma unroll
            for (int j = 0; j < 4; ++j) {
                int q = l0 + 2 * j;
                float acc = 0.f;
                #pragma unroll
                for (int k = 0; k < L_SEQ; ++k)
                    acc += att[q][k] * V[k * DMODEL + m];
                attv[q * DMODEL + m] = acc;
            }
        }
        __syncthreads();
        // (attV) @ Wo + bo -> x
        {
            float acc[4];
            float bov = bo[m];
            #pragma unroll
            for (int j = 0; j < 4; ++j) acc[j] = bov;
            for (int d = 0; d < DMODEL; ++d) {
                float w = Wo[d * DMODEL + m];
                #pragma unroll
                for (int j = 0; j < 4; ++j)
                    acc[j] += attv[(l0 + 2 * j) * DMODEL + d] * w;
            }
            #pragma unroll
            for (int j = 0; j < 4; ++j) {
                int q = l0 + 2 * j;
                x[b * 2048 + q * 256 + off + m] = acc[j];
            }
        }
        __syncthreads();
    }
}

// ---------------------------------------------------------------------------
// MLP: out(2048,1024) = X(2048,2048) @ W(2048,1024) + b
// fp32 tiled GEMM, 64x64 tile, BK=16, 256 threads, 4x4 micro-tile
// ---------------------------------------------------------------------------
#define BM 64
#define BN 64
#define BK 16
__global__ __launch_bounds__(256) void mlp_gemm(
    const float* __restrict__ X, const float* __restrict__ W,
    const float* __restrict__ bias, float* __restrict__ out)
{
    __shared__ float As[BK][BM + 1];
    __shared__ float Bs[BK][BN];
    const int bm = blockIdx.y * BM;
    const int bn = blockIdx.x * BN;
    const int tid = threadIdx.x;
    const int tm = (tid / 16) * 4;
    const int tn = (tid % 16) * 4;
    float acc[4][4];
    #pragma unroll
    for (int i = 0; i < 4; ++i)
        #pragma unroll
        for (int j = 0; j < 4; ++j) acc[i][j] = 0.f;

    for (int k0 = 0; k0 < 2048; k0 += BK) {
        for (int i = tid; i < BM * BK; i += 256) {
            int mm = i / BK, kk = i % BK;
            As[kk][mm] = X[(bm + mm) * 2048 + k0 + kk];
        }
        for (int i = tid; i < BK * BN; i += 256) {
            int kk = i / BN, nn = i % BN;
            Bs[kk][nn] = W[(k0 + kk) * 1024 + bn + nn];
        }
        __syncthreads();
        #pragma unroll
        for (int k = 0; k < BK; ++k) {
            float a[4], bb[4];
            #pragma unroll
            for (int i = 0; i < 4; ++i) a[i] = As[k][tm + i];
            #pragma unroll
            for (int j = 0; j < 4; ++j) bb[j] = Bs[k][tn + j];
            #pragma unroll
            for (int i = 0; i < 4; ++i)
                #pragma unroll
                for (int j = 0; j < 4; ++j)
                    acc[i][j] += a[i] * bb[j];
        }
        __syncthreads();
    }
    #pragma unroll
    for (int i = 0; i < 4; ++i)
        #pragma unroll
        for (int j = 0; j < 4; ++j)
            out[(bm + tm + i) * 1024 + bn + tn + j] = acc[i][j] + bias[bn + tn + j];
}

extern "C" void kernel_launch(void* const* d_in, const int* in_sizes, int n_in,
                              void* d_out, int out_size, void* d_ws, size_t ws_size,
                              hipStream_t stream) {
    const float* st_feature = (const float*)d_in[0];
    const float* exp_feature = (const float*)d_in[1];
    // st mamba params
    const float* st_Win = (const float*)d_in[2];
    const float* st_convw = (const float*)d_in[3];
    const float* st_convb = (const float*)d_in[4];
    const float* st_dtb = (const float*)d_in[5];
    const float* st_Alog = (const float*)d_in[6];
    const float* st_D = (const float*)d_in[7];
    const float* st_normw = (const float*)d_in[8];
    const float* st_Wout = (const float*)d_in[9];
    // ex mamba params
    const float* ex_Win = (const float*)d_in[10];
    const float* ex_convw = (const float*)d_in[11];
    const float* ex_convb = (const float*)d_in[12];
    const float* ex_dtb = (const float*)d_in[13];
    const float* ex_Alog = (const float*)d_in[14];
    const float* ex_D = (const float*)d_in[15];
    const float* ex_normw = (const float*)d_in[16];
    const float* ex_Wout = (const float*)d_in[17];
    // cross-attn params
    const float* cx_Wq = (const float*)d_in[18]; const float* cx_bq = (const float*)d_in[19];
    const float* cx_Wk = (const float*)d_in[20]; const float* cx_bk = (const float*)d_in[21];
    const float* cx_Wv = (const float*)d_in[22]; const float* cx_bv = (const float*)d_in[23];
    const float* cx_Wo = (const float*)d_in[24]; const float* cx_bo = (const float*)d_in[25];
    const float* cs_Wq = (const float*)d_in[26]; const float* cs_bq = (const float*)d_in[27];
    const float* cs_Wk = (const float*)d_in[28]; const float* cs_bk = (const float*)d_in[29];
    const float* cs_Wv = (const float*)d_in[30]; const float* cs_bv = (const float*)d_in[31];
    const float* cs_Wo = (const float*)d_in[32]; const float* cs_bo = (const float*)d_in[33];
    const float* mlp_W = (const float*)d_in[34];
    const float* mlp_b = (const float*)d_in[35];

    float* ws = (float*)d_ws;
    float* st_f = ws;                               // 2048*8*128 = 2M floats
    float* exp_f = ws + (size_t)B_SZ * L_SEQ * DMODEL;
    float* xbuf = ws + 2 * (size_t)B_SZ * L_SEQ * DMODEL;  // 2048*2048

    mamba_kernel<<<B_SZ, 256, 0, stream>>>(exp_feature, ex_Win, ex_convw, ex_convb,
                                           ex_dtb, ex_Alog, ex_D, ex_normw, ex_Wout, exp_f);
    mamba_kernel<<<B_SZ, 256, 0, stream>>>(st_feature, st_Win, st_convw, st_convb,
                                           st_dtb, st_Alog, st_D, st_normw, st_Wout, st_f);
    attn_kernel<<<B_SZ, 256, 0, stream>>>(st_f, exp_f,
                                          cs_Wq, cs_bq, cs_Wk, cs_bk, cs_Wv, cs_bv, cs_Wo, cs_bo,
                                          cx_Wq, cx_bq, cx_Wk, cx_bk, cx_Wv, cx_bv, cx_Wo, cx_bo,
                                          xbuf);
    dim3 grid(1024 / BN, 2048 / BM);
    mlp_gemm<<<grid, 256, 0, stream>>>(xbuf, mlp_W, mlp_b, (float*)d_out);
}

// Round 2
// 552.431 us; speedup vs baseline: 1.5482x; 1.5482x over previous
//
#include <hip/hip_runtime.h>
#include <hip/hip_bf16.h>
#include <math.h>

#define B_SZ 2048
#define L_SEQ 8
#define DMODEL 128
#define DSTATE 64
#define HEADDIM 32
#define DCONV 4
#define DINNER 256
#define NHEADS 8
#define DCONVCH 384   // DINNER + 2*DSTATE
#define DINPROJ 648   // 2*DINNER + 2*DSTATE + NHEADS

typedef short bf16x8 __attribute__((ext_vector_type(8)));
typedef float floatx4 __attribute__((ext_vector_type(4)));

__device__ __forceinline__ float siluf(float x) {
    return x / (1.f + expf(-x));
}

// ---------------------------------------------------------------------------
// Mamba2 block: one workgroup per batch element (unchanged from R1).
// ---------------------------------------------------------------------------
__global__ __launch_bounds__(256) void mamba_kernel(
    const float* __restrict__ u,      // (B, 8, 128)
    const float* __restrict__ Win,    // (128, 648)
    const float* __restrict__ convw,  // (4, 384)
    const float* __restrict__ convb,  // (384)
    const float* __restrict__ dtb,    // (8)
    const float* __restrict__ Alog,   // (8)
    const float* __restrict__ Dp,     // (8)
    const float* __restrict__ normw,  // (256)
    const float* __restrict__ Wout,   // (256, 128)
    float* __restrict__ outf)         // (B, 8, 128)
{
    const int b = blockIdx.x;
    const int tid = threadIdx.x;

    __shared__ float u_s[L_SEQ * DMODEL];
    __shared__ float zx[L_SEQ * DINPROJ];
    __shared__ float xBC[L_SEQ * DCONVCH];
    __shared__ float dtv[L_SEQ][NHEADS];
    __shared__ float cum[L_SEQ][NHEADS];
    __shared__ float Gm[L_SEQ][L_SEQ];
    __shared__ float coef[L_SEQ][L_SEQ][NHEADS];
    __shared__ float y[L_SEQ * DINNER];
    __shared__ float red[L_SEQ][32];
    __shared__ float rstd[L_SEQ];

    for (int i = tid; i < L_SEQ * DMODEL; i += 256)
        u_s[i] = u[b * (L_SEQ * DMODEL) + i];
    __syncthreads();

    for (int j = tid; j < DINPROJ; j += 256) {
        float acc[L_SEQ];
        #pragma unroll
        for (int l = 0; l < L_SEQ; ++l) acc[l] = 0.f;
        for (int k = 0; k < DMODEL; ++k) {
            float w = Win[k * DINPROJ + j];
            #pragma unroll
            for (int l = 0; l < L_SEQ; ++l)
                acc[l] += u_s[l * DMODEL + k] * w;
        }
        #pragma unroll
        for (int l = 0; l < L_SEQ; ++l) zx[l * DINPROJ + j] = acc[l];
    }
    __syncthreads();

    for (int i = tid; i < L_SEQ * DCONVCH; i += 256) {
        int l = i / DCONVCH, c = i % DCONVCH;
        float s = convb[c];
        #pragma unroll
        for (int k = 0; k < DCONV; ++k) {
            int lp = l + k - (DCONV - 1);
            if (lp >= 0) s += zx[lp * DINPROJ + DINNER + c] * convw[k * DCONVCH + c];
        }
        xBC[i] = siluf(s);
    }
    if (tid < L_SEQ * NHEADS) {
        int l = tid / NHEADS, h = tid % NHEADS;
        float v = zx[l * DINPROJ + 2 * DINNER + 2 * DSTATE + h] + dtb[h];
        dtv[l][h] = (v > 20.f) ? v : log1pf(expf(v));
    }
    __syncthreads();
    if (tid < NHEADS) {
        float c = 0.f;
        for (int l = 0; l < L_SEQ; ++l) { c += dtv[l][tid]; cum[l][tid] = c; }
    }
    if (tid >= 64 && tid < 128) {
        int i = tid - 64;
        int t = i / L_SEQ, s = i % L_SEQ;
        float acc = 0.f;
        for (int n = 0; n < DSTATE; ++n)
            acc += xBC[s * DCONVCH + DINNER + n] * xBC[t * DCONVCH + DINNER + DSTATE + n];
        Gm[t][s] = acc;
    }
    __syncthreads();
    for (int i = tid; i < L_SEQ * L_SEQ * NHEADS; i += 256) {
        int t = i / (L_SEQ * NHEADS), s = (i / NHEADS) % L_SEQ, h = i % NHEADS;
        float A = -expf(Alog[h]);
        coef[t][s][h] = (s <= t)
            ? Gm[t][s] * expf(A * (cum[t][h] - cum[s][h])) * dtv[s][h]
            : 0.f;
    }
    __syncthreads();
    for (int i = tid; i < L_SEQ * DINNER; i += 256) {
        int t = i / DINNER, c = i % DINNER;
        int h = c / HEADDIM;
        float acc = Dp[h] * xBC[t * DCONVCH + c];
        for (int s = 0; s <= t; ++s)
            acc += coef[t][s][h] * xBC[s * DCONVCH + c];
        y[i] = acc;
    }
    __syncthreads();
    for (int i = tid; i < L_SEQ * DINNER; i += 256) {
        int l = i / DINNER, c = i % DINNER;
        float zv = zx[l * DINPROJ + c];
        y[i] = y[i] * siluf(zv);
    }
    __syncthreads();
    {
        int l = tid / 32, j = tid % 32;
        float p = 0.f;
        #pragma unroll
        for (int c = j * 8; c < j * 8 + 8; ++c) {
            float v = y[l * DINNER + c];
            p += v * v;
        }
        red[l][j] = p;
    }
    __syncthreads();
    if (tid < L_SEQ) {
        float s = 0.f;
        for (int j = 0; j < 32; ++j) s += red[tid][j];
        rstd[tid] = rsqrtf(s / (float)DINNER + 1e-5f);
    }
    __syncthreads();
    for (int i = tid; i < L_SEQ * DINNER; i += 256) {
        int l = i / DINNER, c = i % DINNER;
        y[i] = y[i] * rstd[l] * normw[c];
    }
    __syncthreads();
    if (tid < DMODEL) {
        int m = tid;
        float acc[L_SEQ];
        #pragma unroll
        for (int l = 0; l < L_SEQ; ++l) acc[l] = 0.f;
        for (int c = 0; c < DINNER; ++c) {
            float w = Wout[c * DMODEL + m];
            #pragma unroll
            for (int l = 0; l < L_SEQ; ++l)
                acc[l] += y[l * DINNER + c] * w;
        }
        #pragma unroll
        for (int l = 0; l < L_SEQ; ++l)
            outf[(b * L_SEQ + l) * DMODEL + m] = acc[l];
    }
}

// ---------------------------------------------------------------------------
// Both cross-attentions; writes X matrix for MLP in bf16.
// ---------------------------------------------------------------------------
__global__ __launch_bounds__(256) void attn_kernel(
    const float* __restrict__ st_f,
    const float* __restrict__ exp_f,
    const float* __restrict__ cs_Wq, const float* __restrict__ cs_bq,
    const float* __restrict__ cs_Wk, const float* __restrict__ cs_bk,
    const float* __restrict__ cs_Wv, const float* __restrict__ cs_bv,
    const float* __restrict__ cs_Wo, const float* __restrict__ cs_bo,
    const float* __restrict__ cx_Wq, const float* __restrict__ cx_bq,
    const float* __restrict__ cx_Wk, const float* __restrict__ cx_bk,
    const float* __restrict__ cx_Wv, const float* __restrict__ cx_bv,
    const float* __restrict__ cx_Wo, const float* __restrict__ cx_bo,
    __hip_bfloat16* __restrict__ x)   // (B, 2048) bf16
{
    const int b = blockIdx.x;
    const int tid = threadIdx.x;
    const float scale = 0.08838834764831845f;

    __shared__ float stf[L_SEQ * DMODEL];
    __shared__ float exf[L_SEQ * DMODEL];
    __shared__ float Q[L_SEQ * DMODEL];
    __shared__ float K[L_SEQ * DMODEL];
    __shared__ float V[L_SEQ * DMODEL];
    __shared__ float att[L_SEQ][L_SEQ];
    __shared__ float attv[L_SEQ * DMODEL];

    for (int i = tid; i < L_SEQ * DMODEL; i += 256) {
        stf[i] = st_f[b * (L_SEQ * DMODEL) + i];
        exf[i] = exp_f[b * (L_SEQ * DMODEL) + i];
    }
    __syncthreads();

    const int m = tid & 127;
    const int l0 = tid >> 7;

    for (int pass = 0; pass < 2; ++pass) {
        const float* qsrc = pass ? exf : stf;
        const float* kvsrc = pass ? stf : exf;
        const float* Wq = pass ? cx_Wq : cs_Wq;  const float* bq = pass ? cx_bq : cs_bq;
        const float* Wk = pass ? cx_Wk : cs_Wk;  const float* bk = pass ? cx_bk : cs_bk;
        const float* Wv = pass ? cx_Wv : cs_Wv;  const float* bv = pass ? cx_bv : cs_bv;
        const float* Wo = pass ? cx_Wo : cs_Wo;  const float* bo = pass ? cx_bo : cs_bo;
        const int off = pass ? DMODEL : 0;

        {
            float aq[4], ak[4], av[4];
            float bqv = bq[m], bkv = bk[m], bvv = bv[m];
            #pragma unroll
            for (int j = 0; j < 4; ++j) { aq[j] = bqv; ak[j] = bkv; av[j] = bvv; }
            for (int k = 0; k < DMODEL; ++k) {
                float wq = Wq[k * DMODEL + m];
                float wk = Wk[k * DMODEL + m];
                float wv = Wv[k * DMODEL + m];
                #pragma unroll
                for (int j = 0; j < 4; ++j) {
                    int l = l0 + 2 * j;
                    float qv = qsrc[l * DMODEL + k];
                    float kv = kvsrc[l * DMODEL + k];
                    aq[j] += qv * wq;
                    ak[j] += kv * wk;
                    av[j] += kv * wv;
                }
            }
            #pragma unroll
            for (int j = 0; j < 4; ++j) {
                int l = l0 + 2 * j;
                Q[l * DMODEL + m] = aq[j];
                K[l * DMODEL + m] = ak[j];
                V[l * DMODEL + m] = av[j];
            }
        }
        __syncthreads();

        if (tid < 64) {
            int q = tid / L_SEQ, k = tid % L_SEQ;
            float s = 0.f;
            for (int d = 0; d < DMODEL; ++d)
                s += Q[q * DMODEL + d] * K[k * DMODEL + d];
            att[q][k] = s * scale;
        }
        __syncthreads();
        if (tid < L_SEQ) {
            int q = tid;
            float mx = -1e30f;
            #pragma unroll
            for (int k = 0; k < L_SEQ; ++k) mx = fmaxf(mx, att[q][k]);
            float sum = 0.f;
            #pragma unroll
            for (int k = 0; k < L_SEQ; ++k) {
                float e = expf(att[q][k] - mx);
                att[q][k] = e;
                sum += e;
            }
            float inv = 1.f / sum;
            #pragma unroll
            for (int k = 0; k < L_SEQ; ++k) att[q][k] *= inv;
        }
        __syncthreads();
        {
            #pragma unroll
            for (int j = 0; j < 4; ++j) {
                int q = l0 + 2 * j;
                float acc = 0.f;
                #pragma unroll
                for (int k = 0; k < L_SEQ; ++k)
                    acc += att[q][k] * V[k * DMODEL + m];
                attv[q * DMODEL + m] = acc;
            }
        }
        __syncthreads();
        {
            float acc[4];
            float bov = bo[m];
            #pragma unroll
            for (int j = 0; j < 4; ++j) acc[j] = bov;
            for (int d = 0; d < DMODEL; ++d) {
                float w = Wo[d * DMODEL + m];
                #pragma unroll
                for (int j = 0; j < 4; ++j)
                    acc[j] += attv[(l0 + 2 * j) * DMODEL + d] * w;
            }
            #pragma unroll
            for (int j = 0; j < 4; ++j) {
                int q = l0 + 2 * j;
                x[(size_t)b * 2048 + q * 256 + off + m] = __float2bfloat16(acc[j]);
            }
        }
        __syncthreads();
    }
}

// ---------------------------------------------------------------------------
// Transpose+cast mlp_W: fp32 [2048][1024] -> bf16 Wt [1024][2048] (k-contig)
// ---------------------------------------------------------------------------
__global__ __launch_bounds__(256) void transpose_w_bf16(
    const float* __restrict__ W, unsigned short* __restrict__ Wt)
{
    __shared__ float tile[32][33];
    const int k0 = blockIdx.y * 32;
    const int n0 = blockIdx.x * 32;
    const int tid = threadIdx.x;
    const int c = tid & 31, r0 = tid >> 5;   // 8 row-groups
    for (int rr = r0; rr < 32; rr += 8)
        tile[rr][c] = W[(k0 + rr) * 1024 + n0 + c];
    __syncthreads();
    for (int rr = r0; rr < 32; rr += 8) {
        __hip_bfloat16 v = __float2bfloat16(tile[c][rr]);
        Wt[(size_t)(n0 + rr) * 2048 + k0 + c] = *(unsigned short*)&v;
    }
}

// ---------------------------------------------------------------------------
// MLP via MFMA: out(2048,1024) = X(2048,2048)bf16 @ W(2048,1024)bf16 + b
// 64x64 block tile, 4 waves (2x2), wave tile 32x32 = 2x2 mfma 16x16x32.
// Wt is W transposed (n-major, k-contiguous).
// ---------------------------------------------------------------------------
#define LDT 40   // padded LDS row stride (bf16): 80B = 20 banks -> 2-way only
__global__ __launch_bounds__(256) void mlp_mfma(
    const unsigned short* __restrict__ X,   // [2048][2048] bf16
    const unsigned short* __restrict__ Wt,  // [1024][2048] bf16
    const float* __restrict__ bias,         // [1024]
    float* __restrict__ out)                // [2048][1024]
{
    __shared__ __align__(16) unsigned short As[64 * LDT];
    __shared__ __align__(16) unsigned short Bs[64 * LDT];
    const int tid = threadIdx.x;
    const int wave = tid >> 6, lane = tid & 63;
    const int wm = (wave >> 1) * 32, wn = (wave & 1) * 32;
    const int bm = blockIdx.y * 64, bn = blockIdx.x * 64;

    const int lrow = tid >> 2;          // 0..63
    const int lcol = (tid & 3) * 8;     // 0,8,16,24

    const int l15 = lane & 15;
    const int q8 = (lane >> 4) * 8;

    floatx4 acc00 = {0.f, 0.f, 0.f, 0.f};
    floatx4 acc01 = {0.f, 0.f, 0.f, 0.f};
    floatx4 acc10 = {0.f, 0.f, 0.f, 0.f};
    floatx4 acc11 = {0.f, 0.f, 0.f, 0.f};

    const unsigned short* gA = X + (size_t)(bm + lrow) * 2048 + lcol;
    const unsigned short* gB = Wt + (size_t)(bn + lrow) * 2048 + lcol;

    for (int k0 = 0; k0 < 2048; k0 += 32) {
        uint4 av = *(const uint4*)(gA + k0);
        uint4 bv = *(const uint4*)(gB + k0);
        __syncthreads();                       // previous iter's reads done
        *(uint4*)(As + lrow * LDT + lcol) = av;
        *(uint4*)(Bs + lrow * LDT + lcol) = bv;
        __syncthreads();
        bf16x8 a0 = *(const bf16x8*)(As + (wm + l15) * LDT + q8);
        bf16x8 a1 = *(const bf16x8*)(As + (wm + 16 + l15) * LDT + q8);
        bf16x8 b0 = *(const bf16x8*)(Bs + (wn + l15) * LDT + q8);
        bf16x8 b1 = *(const bf16x8*)(Bs + (wn + 16 + l15) * LDT + q8);
        acc00 = __builtin_amdgcn_mfma_f32_16x16x32_bf16(a0, b0, acc00, 0, 0, 0);
        acc01 = __builtin_amdgcn_mfma_f32_16x16x32_bf16(a0, b1, acc01, 0, 0, 0);
        acc10 = __builtin_amdgcn_mfma_f32_16x16x32_bf16(a1, b0, acc10, 0, 0, 0);
        acc11 = __builtin_amdgcn_mfma_f32_16x16x32_bf16(a1, b1, acc11, 0, 0, 0);
    }

    // C/D layout: col = lane&15, row = (lane>>4)*4 + reg  [m89]
    const int row0 = (lane >> 4) * 4;
    #pragma unroll
    for (int j = 0; j < 2; ++j) {
        int col = bn + wn + j * 16 + l15;
        float bv = bias[col];
        floatx4 aj0 = j ? acc01 : acc00;
        floatx4 aj1 = j ? acc11 : acc10;
        #pragma unroll
        for (int r = 0; r < 4; ++r) {
            out[(size_t)(bm + wm + row0 + r) * 1024 + col] = aj0[r] + bv;
            out[(size_t)(bm + wm + 16 + row0 + r) * 1024 + col] = aj1[r] + bv;
        }
    }
}

extern "C" void kernel_launch(void* const* d_in, const int* in_sizes, int n_in,
                              void* d_out, int out_size, void* d_ws, size_t ws_size,
                              hipStream_t stream) {
    const float* st_feature = (const float*)d_in[0];
    const float* exp_feature = (const float*)d_in[1];
    const float* st_Win = (const float*)d_in[2];
    const float* st_convw = (const float*)d_in[3];
    const float* st_convb = (const float*)d_in[4];
    const float* st_dtb = (const float*)d_in[5];
    const float* st_Alog = (const float*)d_in[6];
    const float* st_D = (const float*)d_in[7];
    const float* st_normw = (const float*)d_in[8];
    const float* st_Wout = (const float*)d_in[9];
    const float* ex_Win = (const float*)d_in[10];
    const float* ex_convw = (const float*)d_in[11];
    const float* ex_convb = (const float*)d_in[12];
    const float* ex_dtb = (const float*)d_in[13];
    const float* ex_Alog = (const float*)d_in[14];
    const float* ex_D = (const float*)d_in[15];
    const float* ex_normw = (const float*)d_in[16];
    const float* ex_Wout = (const float*)d_in[17];
    const float* cx_Wq = (const float*)d_in[18]; const float* cx_bq = (const float*)d_in[19];
    const float* cx_Wk = (const float*)d_in[20]; const float* cx_bk = (const float*)d_in[21];
    const float* cx_Wv = (const float*)d_in[22]; const float* cx_bv = (const float*)d_in[23];
    const float* cx_Wo = (const float*)d_in[24]; const float* cx_bo = (const float*)d_in[25];
    const float* cs_Wq = (const float*)d_in[26]; const float* cs_bq = (const float*)d_in[27];
    const float* cs_Wk = (const float*)d_in[28]; const float* cs_bk = (const float*)d_in[29];
    const float* cs_Wv = (const float*)d_in[30]; const float* cs_bv = (const float*)d_in[31];
    const float* cs_Wo = (const float*)d_in[32]; const float* cs_bo = (const float*)d_in[33];
    const float* mlp_W = (const float*)d_in[34];
    const float* mlp_b = (const float*)d_in[35];

    float* ws = (float*)d_ws;
    float* st_f = ws;                                   // 2M floats (8 MB)
    float* exp_f = ws + (size_t)B_SZ * L_SEQ * DMODEL;  // 2M floats (8 MB)
    unsigned short* xbuf = (unsigned short*)(ws + 2 * (size_t)B_SZ * L_SEQ * DMODEL); // 4M bf16 (8 MB)
    unsigned short* wtbuf = xbuf + (size_t)2048 * 2048;  // 2M bf16 (4 MB)

    // W transpose/cast can start immediately
    {
        dim3 g(1024 / 32, 2048 / 32);
        transpose_w_bf16<<<g, 256, 0, stream>>>(mlp_W, wtbuf);
    }
    mamba_kernel<<<B_SZ, 256, 0, stream>>>(exp_feature, ex_Win, ex_convw, ex_convb,
                                           ex_dtb, ex_Alog, ex_D, ex_normw, ex_Wout, exp_f);
    mamba_kernel<<<B_SZ, 256, 0, stream>>>(st_feature, st_Win, st_convw, st_convb,
                                           st_dtb, st_Alog, st_D, st_normw, st_Wout, st_f);
    attn_kernel<<<B_SZ, 256, 0, stream>>>(st_f, exp_f,
                                          cs_Wq, cs_bq, cs_Wk, cs_bk, cs_Wv, cs_bv, cs_Wo, cs_bo,
                                          cx_Wq, cx_bq, cx_Wk, cx_bk, cx_Wv, cx_bv, cx_Wo, cx_bo,
                                          (__hip_bfloat16*)xbuf);
    {
        dim3 g(1024 / 64, 2048 / 64);
        mlp_mfma<<<g, 256, 0, stream>>>(xbuf, wtbuf, mlp_b, (float*)d_out);
    }
}

// Round 3
// 398.695 us; speedup vs baseline: 2.1452x; 1.3856x over previous
//
#include <hip/hip_runtime.h>
#include <hip/hip_bf16.h>
#include <math.h>

#define B_SZ 2048
#define L_SEQ 8
#define DMODEL 128
#define DSTATE 64
#define HEADDIM 32
#define DCONV 4
#define DINNER 256
#define NHEADS 8
#define DCONVCH 384   // DINNER + 2*DSTATE
#define DINPROJ 648   // 2*DINNER + 2*DSTATE + NHEADS
#define NPAD 656      // 41 * 16

typedef short bf16x8 __attribute__((ext_vector_type(8)));
typedef float floatx4 __attribute__((ext_vector_type(4)));

__device__ __forceinline__ float siluf(float x) {
    return x / (1.f + expf(-x));
}
__device__ __forceinline__ float bf2f(unsigned short h) {
    unsigned int u = ((unsigned int)h) << 16;
    return __builtin_bit_cast(float, u);
}
__device__ __forceinline__ unsigned short f2bf(float f) {
    __hip_bfloat16 b = __float2bfloat16(f);
    return __builtin_bit_cast(unsigned short, b);
}

// ---------------------------------------------------------------------------
// Generic transpose+cast: src fp32 [K][N] -> dst bf16 [n_pad][K] (k-contig),
// rows n >= N zero-filled.
// ---------------------------------------------------------------------------
__global__ __launch_bounds__(256) void transpose_cast(
    const float* __restrict__ src, unsigned short* __restrict__ dst,
    int K, int N, int n_pad)
{
    int idx = blockIdx.x * 256 + threadIdx.x;
    if (idx >= n_pad * K) return;
    int n = idx / K, k = idx % K;
    float v = (n < N) ? src[k * N + n] : 0.f;
    dst[idx] = f2bf(v);
}

// ---------------------------------------------------------------------------
// Mamba2: 2 batches per workgroup (M=16 rows), MFMA in/out projections.
// WinT: bf16 [656][128] (transposed, padded); WoutT: bf16 [128][256].
// ---------------------------------------------------------------------------
#define LDK 136   // uA row stride (bf16)
#define LDZ 660   // zx row stride (bf16)
#define LDX 400   // xBC row stride (bf16)
#define LDY 264   // yb row stride (bf16)
__global__ __launch_bounds__(256) void mamba_kernel(
    const float* __restrict__ u,              // (B, 8, 128)
    const unsigned short* __restrict__ WinT,  // (656, 128) bf16
    const float* __restrict__ convw,          // (4, 384)
    const float* __restrict__ convb,          // (384)
    const float* __restrict__ dtb,            // (8)
    const float* __restrict__ Alog,           // (8)
    const float* __restrict__ Dp,             // (8)
    const float* __restrict__ normw,          // (256)
    const unsigned short* __restrict__ WoutT, // (128, 256) bf16
    float* __restrict__ outf)                 // (B, 8, 128)
{
    const int tid = threadIdx.x;
    const int lane = tid & 63;
    const int wave = tid >> 6;
    const int l15 = lane & 15;
    const int q8 = (lane >> 4) * 8;
    const int row0 = (lane >> 4) * 4;
    const int grow0 = blockIdx.x * 16;   // first global seq-row of this block

    __shared__ __align__(16) unsigned short uA[16 * LDK];
    __shared__ __align__(16) unsigned short zx[16 * LDZ];
    __shared__ __align__(16) unsigned short xBC[16 * LDX];
    __shared__ __align__(16) unsigned short yb[16 * LDY];
    __shared__ float dtraw[16][8];
    __shared__ float dtv[2][8][8];    // [bloc][l][h]
    __shared__ float cum[2][8][8];
    __shared__ float Gm[2][8][8];     // [bloc][t][s]
    __shared__ float coef[2][8][8][8];// [bloc][t][s][h]
    __shared__ float red[16][16];
    __shared__ float rstd[16];

    // --- phase 1: load u rows -> bf16 A-tile ---
    for (int i = tid; i < 512; i += 256) {
        int r = i >> 5, k4 = (i & 31) * 4;
        float4 v = *(const float4*)(u + (size_t)(grow0 + r) * DMODEL + k4);
        ushort4 h;
        h.x = f2bf(v.x); h.y = f2bf(v.y); h.z = f2bf(v.z); h.w = f2bf(v.w);
        *(ushort4*)(uA + r * LDK + k4) = h;
    }
    __syncthreads();

    // --- phase 2: in_proj MFMA: zx[16][648] = uA @ Win ---
    {
        bf16x8 af[4];
        #pragma unroll
        for (int kk = 0; kk < 4; ++kk)
            af[kk] = *(const bf16x8*)(uA + l15 * LDK + kk * 32 + q8);
        for (int nt = wave; nt < 41; nt += 4) {
            floatx4 acc = {0.f, 0.f, 0.f, 0.f};
            const unsigned short* bp = WinT + (size_t)(nt * 16 + l15) * 128 + q8;
            #pragma unroll
            for (int kk = 0; kk < 4; ++kk) {
                bf16x8 bf = *(const bf16x8*)(bp + kk * 32);
                acc = __builtin_amdgcn_mfma_f32_16x16x32_bf16(af[kk], bf, acc, 0, 0, 0);
            }
            if (nt == 40) {
                if (l15 < 8) {
                    #pragma unroll
                    for (int r = 0; r < 4; ++r)
                        dtraw[row0 + r][l15] = acc[r];   // fp32 dt path
                }
            } else {
                #pragma unroll
                for (int r = 0; r < 4; ++r)
                    zx[(row0 + r) * LDZ + nt * 16 + l15] = f2bf(acc[r]);
            }
        }
    }
    __syncthreads();

    // --- phase 3: conv + silu -> xBC ; phase 4a: dt softplus ---
    for (int i = tid; i < 16 * DCONVCH; i += 256) {
        int r = i / DCONVCH, c = i % DCONVCH;
        int bloc = r >> 3, l = r & 7;
        float s = convb[c];
        #pragma unroll
        for (int k = 0; k < DCONV; ++k) {
            int lp = l + k - (DCONV - 1);
            if (lp >= 0)
                s += bf2f(zx[(bloc * 8 + lp) * LDZ + DINNER + c]) * convw[k * DCONVCH + c];
        }
        xBC[r * LDX + c] = f2bf(siluf(s));
    }
    if (tid < 128) {
        int r = tid >> 3, h = tid & 7;
        float v = dtraw[r][h] + dtb[h];
        dtv[r >> 3][r & 7][h] = (v > 20.f) ? v : log1pf(expf(v));
    }
    __syncthreads();

    // --- phase 5: Gm (tid<128) + cum (tid 128..143) ---
    if (tid < 128) {
        int bloc = tid >> 6, t = (tid >> 3) & 7, s = tid & 7;
        float a = 0.f;
        for (int n = 0; n < DSTATE; ++n)
            a += bf2f(xBC[(bloc * 8 + s) * LDX + DINNER + n]) *
                 bf2f(xBC[(bloc * 8 + t) * LDX + DINNER + DSTATE + n]);
        Gm[bloc][t][s] = a;
    } else if (tid < 144) {
        int j = tid - 128;
        int bloc = j >> 3, h = j & 7;
        float c = 0.f;
        for (int l = 0; l < L_SEQ; ++l) { c += dtv[bloc][l][h]; cum[bloc][l][h] = c; }
    }
    __syncthreads();

    // --- phase 6: coef ---
    for (int i = tid; i < 1024; i += 256) {
        int bloc = i >> 9, t = (i >> 6) & 7, s = (i >> 3) & 7, h = i & 7;
        float A = -expf(Alog[h]);
        coef[bloc][t][s][h] = (s <= t)
            ? Gm[bloc][t][s] * expf(A * (cum[bloc][t][h] - cum[bloc][s][h])) * dtv[bloc][s][h]
            : 0.f;
    }
    __syncthreads();

    // --- phase 7: y scan + gate ---
    for (int i = tid; i < 16 * DINNER; i += 256) {
        int r = i >> 8, c = i & 255;
        int bloc = r >> 3, t = r & 7, h = c >> 5;
        float acc = Dp[h] * bf2f(xBC[r * LDX + c]);
        for (int s = 0; s <= t; ++s)
            acc += coef[bloc][t][s][h] * bf2f(xBC[(bloc * 8 + s) * LDX + c]);
        float z = bf2f(zx[r * LDZ + c]);
        yb[r * LDY + c] = f2bf(acc * siluf(z));
    }
    __syncthreads();

    // --- rmsnorm ---
    {
        int r = tid >> 4, j = tid & 15;
        float p = 0.f;
        #pragma unroll
        for (int c = j * 16; c < j * 16 + 16; ++c) {
            float v = bf2f(yb[r * LDY + c]);
            p += v * v;
        }
        red[r][j] = p;
    }
    __syncthreads();
    if (tid < 16) {
        float s = 0.f;
        #pragma unroll
        for (int j = 0; j < 16; ++j) s += red[tid][j];
        rstd[tid] = rsqrtf(s / (float)DINNER + 1e-5f);
    }
    __syncthreads();
    for (int i = tid; i < 16 * DINNER; i += 256) {
        int r = i >> 8, c = i & 255;
        yb[r * LDY + c] = f2bf(bf2f(yb[r * LDY + c]) * rstd[r] * normw[c]);
    }
    __syncthreads();

    // --- phase 9: out_proj MFMA: outf[16][128] = yb @ Wout ---
    {
        bf16x8 af[8];
        #pragma unroll
        for (int kk = 0; kk < 8; ++kk)
            af[kk] = *(const bf16x8*)(yb + l15 * LDY + kk * 32 + q8);
        #pragma unroll
        for (int ni = 0; ni < 2; ++ni) {
            int nt = wave * 2 + ni;
            floatx4 acc = {0.f, 0.f, 0.f, 0.f};
            const unsigned short* bp = WoutT + (size_t)(nt * 16 + l15) * 256 + q8;
            #pragma unroll
            for (int kk = 0; kk < 8; ++kk) {
                bf16x8 bf = *(const bf16x8*)(bp + kk * 32);
                acc = __builtin_amdgcn_mfma_f32_16x16x32_bf16(af[kk], bf, acc, 0, 0, 0);
            }
            #pragma unroll
            for (int r = 0; r < 4; ++r)
                outf[(size_t)(grow0 + row0 + r) * DMODEL + nt * 16 + l15] = acc[r];
        }
    }
}

// ---------------------------------------------------------------------------
// Both cross-attentions; writes X matrix for MLP in bf16. (unchanged)
// ---------------------------------------------------------------------------
__global__ __launch_bounds__(256) void attn_kernel(
    const float* __restrict__ st_f,
    const float* __restrict__ exp_f,
    const float* __restrict__ cs_Wq, const float* __restrict__ cs_bq,
    const float* __restrict__ cs_Wk, const float* __restrict__ cs_bk,
    const float* __restrict__ cs_Wv, const float* __restrict__ cs_bv,
    const float* __restrict__ cs_Wo, const float* __restrict__ cs_bo,
    const float* __restrict__ cx_Wq, const float* __restrict__ cx_bq,
    const float* __restrict__ cx_Wk, const float* __restrict__ cx_bk,
    const float* __restrict__ cx_Wv, const float* __restrict__ cx_bv,
    const float* __restrict__ cx_Wo, const float* __restrict__ cx_bo,
    __hip_bfloat16* __restrict__ x)   // (B, 2048) bf16
{
    const int b = blockIdx.x;
    const int tid = threadIdx.x;
    const float scale = 0.08838834764831845f;

    __shared__ float stf[L_SEQ * DMODEL];
    __shared__ float exf[L_SEQ * DMODEL];
    __shared__ float Q[L_SEQ * DMODEL];
    __shared__ float K[L_SEQ * DMODEL];
    __shared__ float V[L_SEQ * DMODEL];
    __shared__ float att[L_SEQ][L_SEQ];
    __shared__ float attv[L_SEQ * DMODEL];

    for (int i = tid; i < L_SEQ * DMODEL; i += 256) {
        stf[i] = st_f[b * (L_SEQ * DMODEL) + i];
        exf[i] = exp_f[b * (L_SEQ * DMODEL) + i];
    }
    __syncthreads();

    const int m = tid & 127;
    const int l0 = tid >> 7;

    for (int pass = 0; pass < 2; ++pass) {
        const float* qsrc = pass ? exf : stf;
        const float* kvsrc = pass ? stf : exf;
        const float* Wq = pass ? cx_Wq : cs_Wq;  const float* bq = pass ? cx_bq : cs_bq;
        const float* Wk = pass ? cx_Wk : cs_Wk;  const float* bk = pass ? cx_bk : cs_bk;
        const float* Wv = pass ? cx_Wv : cs_Wv;  const float* bv = pass ? cx_bv : cs_bv;
        const float* Wo = pass ? cx_Wo : cs_Wo;  const float* bo = pass ? cx_bo : cs_bo;
        const int off = pass ? DMODEL : 0;

        {
            float aq[4], ak[4], av[4];
            float bqv = bq[m], bkv = bk[m], bvv = bv[m];
            #pragma unroll
            for (int j = 0; j < 4; ++j) { aq[j] = bqv; ak[j] = bkv; av[j] = bvv; }
            for (int k = 0; k < DMODEL; ++k) {
                float wq = Wq[k * DMODEL + m];
                float wk = Wk[k * DMODEL + m];
                float wv = Wv[k * DMODEL + m];
                #pragma unroll
                for (int j = 0; j < 4; ++j) {
                    int l = l0 + 2 * j;
                    float qv = qsrc[l * DMODEL + k];
                    float kv = kvsrc[l * DMODEL + k];
                    aq[j] += qv * wq;
                    ak[j] += kv * wk;
                    av[j] += kv * wv;
                }
            }
            #pragma unroll
            for (int j = 0; j < 4; ++j) {
                int l = l0 + 2 * j;
                Q[l * DMODEL + m] = aq[j];
                K[l * DMODEL + m] = ak[j];
                V[l * DMODEL + m] = av[j];
            }
        }
        __syncthreads();

        if (tid < 64) {
            int q = tid / L_SEQ, k = tid % L_SEQ;
            float s = 0.f;
            for (int d = 0; d < DMODEL; ++d)
                s += Q[q * DMODEL + d] * K[k * DMODEL + d];
            att[q][k] = s * scale;
        }
        __syncthreads();
        if (tid < L_SEQ) {
            int q = tid;
            float mx = -1e30f;
            #pragma unroll
            for (int k = 0; k < L_SEQ; ++k) mx = fmaxf(mx, att[q][k]);
            float sum = 0.f;
            #pragma unroll
            for (int k = 0; k < L_SEQ; ++k) {
                float e = expf(att[q][k] - mx);
                att[q][k] = e;
                sum += e;
            }
            float inv = 1.f / sum;
            #pragma unroll
            for (int k = 0; k < L_SEQ; ++k) att[q][k] *= inv;
        }
        __syncthreads();
        {
            #pragma unroll
            for (int j = 0; j < 4; ++j) {
                int q = l0 + 2 * j;
                float acc = 0.f;
                #pragma unroll
                for (int k = 0; k < L_SEQ; ++k)
                    acc += att[q][k] * V[k * DMODEL + m];
                attv[q * DMODEL + m] = acc;
            }
        }
        __syncthreads();
        {
            float acc[4];
            float bov = bo[m];
            #pragma unroll
            for (int j = 0; j < 4; ++j) acc[j] = bov;
            for (int d = 0; d < DMODEL; ++d) {
                float w = Wo[d * DMODEL + m];
                #pragma unroll
                for (int j = 0; j < 4; ++j)
                    acc[j] += attv[(l0 + 2 * j) * DMODEL + d] * w;
            }
            #pragma unroll
            for (int j = 0; j < 4; ++j) {
                int q = l0 + 2 * j;
                x[(size_t)b * 2048 + q * 256 + off + m] = __float2bfloat16(acc[j]);
            }
        }
        __syncthreads();
    }
}

// ---------------------------------------------------------------------------
// Tiled transpose+cast for the big MLP weight (coalesced).
// ---------------------------------------------------------------------------
__global__ __launch_bounds__(256) void transpose_w_bf16(
    const float* __restrict__ W, unsigned short* __restrict__ Wt)
{
    __shared__ float tile[32][33];
    const int k0 = blockIdx.y * 32;
    const int n0 = blockIdx.x * 32;
    const int tid = threadIdx.x;
    const int c = tid & 31, r0 = tid >> 5;
    for (int rr = r0; rr < 32; rr += 8)
        tile[rr][c] = W[(k0 + rr) * 1024 + n0 + c];
    __syncthreads();
    for (int rr = r0; rr < 32; rr += 8)
        Wt[(size_t)(n0 + rr) * 2048 + k0 + c] = f2bf(tile[c][rr]);
}

// ---------------------------------------------------------------------------
// MLP via MFMA (unchanged from R2).
// ---------------------------------------------------------------------------
#define LDT 40
__global__ __launch_bounds__(256) void mlp_mfma(
    const unsigned short* __restrict__ X,
    const unsigned short* __restrict__ Wt,
    const float* __restrict__ bias,
    float* __restrict__ out)
{
    __shared__ __align__(16) unsigned short As[64 * LDT];
    __shared__ __align__(16) unsigned short Bs[64 * LDT];
    const int tid = threadIdx.x;
    const int wave = tid >> 6, lane = tid & 63;
    const int wm = (wave >> 1) * 32, wn = (wave & 1) * 32;
    const int bm = blockIdx.y * 64, bn = blockIdx.x * 64;

    const int lrow = tid >> 2;
    const int lcol = (tid & 3) * 8;
    const int l15 = lane & 15;
    const int q8 = (lane >> 4) * 8;

    floatx4 acc00 = {0.f, 0.f, 0.f, 0.f};
    floatx4 acc01 = {0.f, 0.f, 0.f, 0.f};
    floatx4 acc10 = {0.f, 0.f, 0.f, 0.f};
    floatx4 acc11 = {0.f, 0.f, 0.f, 0.f};

    const unsigned short* gA = X + (size_t)(bm + lrow) * 2048 + lcol;
    const unsigned short* gB = Wt + (size_t)(bn + lrow) * 2048 + lcol;

    for (int k0 = 0; k0 < 2048; k0 += 32) {
        uint4 av = *(const uint4*)(gA + k0);
        uint4 bv = *(const uint4*)(gB + k0);
        __syncthreads();
        *(uint4*)(As + lrow * LDT + lcol) = av;
        *(uint4*)(Bs + lrow * LDT + lcol) = bv;
        __syncthreads();
        bf16x8 a0 = *(const bf16x8*)(As + (wm + l15) * LDT + q8);
        bf16x8 a1 = *(const bf16x8*)(As + (wm + 16 + l15) * LDT + q8);
        bf16x8 b0 = *(const bf16x8*)(Bs + (wn + l15) * LDT + q8);
        bf16x8 b1 = *(const bf16x8*)(Bs + (wn + 16 + l15) * LDT + q8);
        acc00 = __builtin_amdgcn_mfma_f32_16x16x32_bf16(a0, b0, acc00, 0, 0, 0);
        acc01 = __builtin_amdgcn_mfma_f32_16x16x32_bf16(a0, b1, acc01, 0, 0, 0);
        acc10 = __builtin_amdgcn_mfma_f32_16x16x32_bf16(a1, b0, acc10, 0, 0, 0);
        acc11 = __builtin_amdgcn_mfma_f32_16x16x32_bf16(a1, b1, acc11, 0, 0, 0);
    }

    const int row0 = (lane >> 4) * 4;
    #pragma unroll
    for (int j = 0; j < 2; ++j) {
        int col = bn + wn + j * 16 + l15;
        float bv = bias[col];
        floatx4 aj0 = j ? acc01 : acc00;
        floatx4 aj1 = j ? acc11 : acc10;
        #pragma unroll
        for (int r = 0; r < 4; ++r) {
            out[(size_t)(bm + wm + row0 + r) * 1024 + col] = aj0[r] + bv;
            out[(size_t)(bm + wm + 16 + row0 + r) * 1024 + col] = aj1[r] + bv;
        }
    }
}

extern "C" void kernel_launch(void* const* d_in, const int* in_sizes, int n_in,
                              void* d_out, int out_size, void* d_ws, size_t ws_size,
                              hipStream_t stream) {
    const float* st_feature = (const float*)d_in[0];
    const float* exp_feature = (const float*)d_in[1];
    const float* st_Win = (const float*)d_in[2];
    const float* st_convw = (const float*)d_in[3];
    const float* st_convb = (const float*)d_in[4];
    const float* st_dtb = (const float*)d_in[5];
    const float* st_Alog = (const float*)d_in[6];
    const float* st_D = (const float*)d_in[7];
    const float* st_normw = (const float*)d_in[8];
    const float* st_Wout = (const float*)d_in[9];
    const float* ex_Win = (const float*)d_in[10];
    const float* ex_convw = (const float*)d_in[11];
    const float* ex_convb = (const float*)d_in[12];
    const float* ex_dtb = (const float*)d_in[13];
    const float* ex_Alog = (const float*)d_in[14];
    const float* ex_D = (const float*)d_in[15];
    const float* ex_normw = (const float*)d_in[16];
    const float* ex_Wout = (const float*)d_in[17];
    const float* cx_Wq = (const float*)d_in[18]; const float* cx_bq = (const float*)d_in[19];
    const float* cx_Wk = (const float*)d_in[20]; const float* cx_bk = (const float*)d_in[21];
    const float* cx_Wv = (const float*)d_in[22]; const float* cx_bv = (const float*)d_in[23];
    const float* cx_Wo = (const float*)d_in[24]; const float* cx_bo = (const float*)d_in[25];
    const float* cs_Wq = (const float*)d_in[26]; const float* cs_bq = (const float*)d_in[27];
    const float* cs_Wk = (const float*)d_in[28]; const float* cs_bk = (const float*)d_in[29];
    const float* cs_Wv = (const float*)d_in[30]; const float* cs_bv = (const float*)d_in[31];
    const float* cs_Wo = (const float*)d_in[32]; const float* cs_bo = (const float*)d_in[33];
    const float* mlp_W = (const float*)d_in[34];
    const float* mlp_b = (const float*)d_in[35];

    float* ws = (float*)d_ws;
    float* st_f = ws;                                   // 2M floats
    float* exp_f = ws + (size_t)B_SZ * L_SEQ * DMODEL;  // 2M floats
    unsigned short* xbuf = (unsigned short*)(ws + 2 * (size_t)B_SZ * L_SEQ * DMODEL); // 4M bf16
    unsigned short* wtbuf = xbuf + (size_t)2048 * 2048;      // 2M bf16
    unsigned short* winT_st = wtbuf + (size_t)1024 * 2048;   // 656*128
    unsigned short* winT_ex = winT_st + (size_t)NPAD * 128;
    unsigned short* woutT_st = winT_ex + (size_t)NPAD * 128; // 128*256
    unsigned short* woutT_ex = woutT_st + (size_t)128 * 256;

    // weight prep (graph-capture-safe, all on stream)
    transpose_cast<<<(NPAD * 128 + 255) / 256, 256, 0, stream>>>(st_Win, winT_st, 128, DINPROJ, NPAD);
    transpose_cast<<<(NPAD * 128 + 255) / 256, 256, 0, stream>>>(ex_Win, winT_ex, 128, DINPROJ, NPAD);
    transpose_cast<<<(128 * 256 + 255) / 256, 256, 0, stream>>>(st_Wout, woutT_st, 256, 128, 128);
    transpose_cast<<<(128 * 256 + 255) / 256, 256, 0, stream>>>(ex_Wout, woutT_ex, 256, 128, 128);
    {
        dim3 g(1024 / 32, 2048 / 32);
        transpose_w_bf16<<<g, 256, 0, stream>>>(mlp_W, wtbuf);
    }

    mamba_kernel<<<B_SZ / 2, 256, 0, stream>>>(exp_feature, winT_ex, ex_convw, ex_convb,
                                               ex_dtb, ex_Alog, ex_D, ex_normw, woutT_ex, exp_f);
    mamba_kernel<<<B_SZ / 2, 256, 0, stream>>>(st_feature, winT_st, st_convw, st_convb,
                                               st_dtb, st_Alog, st_D, st_normw, woutT_st, st_f);
    attn_kernel<<<B_SZ, 256, 0, stream>>>(st_f, exp_f,
                                          cs_Wq, cs_bq, cs_Wk, cs_bk, cs_Wv, cs_bv, cs_Wo, cs_bo,
                                          cx_Wq, cx_bq, cx_Wk, cx_bk, cx_Wv, cx_bv, cx_Wo, cx_bo,
                                          (__hip_bfloat16*)xbuf);
    {
        dim3 g(1024 / 64, 2048 / 64);
        mlp_mfma<<<g, 256, 0, stream>>>(xbuf, wtbuf, mlp_b, (float*)d_out);
    }
}

// Round 4
// 336.229 us; speedup vs baseline: 2.5438x; 1.1858x over previous
//
#include <hip/hip_runtime.h>
#include <hip/hip_bf16.h>
#include <math.h>

#define B_SZ 2048
#define L_SEQ 8
#define DMODEL 128
#define DSTATE 64
#define HEADDIM 32
#define DCONV 4
#define DINNER 256
#define NHEADS 8
#define DCONVCH 384   // DINNER + 2*DSTATE
#define DINPROJ 648   // 2*DINNER + 2*DSTATE + NHEADS
#define NPAD 656      // 41 * 16

typedef short bf16x8 __attribute__((ext_vector_type(8)));
typedef float floatx4 __attribute__((ext_vector_type(4)));

__device__ __forceinline__ float siluf(float x) {
    return x / (1.f + expf(-x));
}
__device__ __forceinline__ float bf2f(unsigned short h) {
    unsigned int u = ((unsigned int)h) << 16;
    return __builtin_bit_cast(float, u);
}
__device__ __forceinline__ unsigned short f2bf(float f) {
    __hip_bfloat16 b = __float2bfloat16(f);
    return __builtin_bit_cast(unsigned short, b);
}

// ---------------------------------------------------------------------------
// Generic transpose+cast: src fp32 [K][N] -> dst bf16 [n_pad][K] (k-contig)
// ---------------------------------------------------------------------------
__global__ __launch_bounds__(256) void transpose_cast(
    const float* __restrict__ src, unsigned short* __restrict__ dst,
    int K, int N, int n_pad)
{
    int idx = blockIdx.x * 256 + threadIdx.x;
    if (idx >= n_pad * K) return;
    int n = idx / K, k = idx % K;
    float v = (n < N) ? src[k * N + n] : 0.f;
    dst[idx] = f2bf(v);
}

// ---------------------------------------------------------------------------
// Merged transpose+cast for the 8 attention 128x128 weights.
// dst layout: 8 contiguous [128][128] bf16 matrices, [n][k] order.
// Order: cs_Wq, cs_Wk, cs_Wv, cs_Wo, cx_Wq, cx_Wk, cx_Wv, cx_Wo
// ---------------------------------------------------------------------------
__global__ __launch_bounds__(256) void transpose_attn_w(
    const float* __restrict__ s0, const float* __restrict__ s1,
    const float* __restrict__ s2, const float* __restrict__ s3,
    const float* __restrict__ s4, const float* __restrict__ s5,
    const float* __restrict__ s6, const float* __restrict__ s7,
    unsigned short* __restrict__ dst)
{
    int idx = blockIdx.x >> 6;           // matrix id, 64 blocks per matrix
    const float* src = idx == 0 ? s0 : idx == 1 ? s1 : idx == 2 ? s2 :
                       idx == 3 ? s3 : idx == 4 ? s4 : idx == 5 ? s5 :
                       idx == 6 ? s6 : s7;
    int e = (blockIdx.x & 63) * 256 + threadIdx.x;
    int n = e >> 7, k = e & 127;
    dst[idx * 16384 + n * 128 + k] = f2bf(src[k * 128 + n]);
}

// ---------------------------------------------------------------------------
// Mamba2: 2 batches per workgroup (M=16 rows), MFMA in/out projections.
// Unchanged from R3 except output is bf16.
// ---------------------------------------------------------------------------
#define LDK 136
#define LDZ 660
#define LDX 400
#define LDY 264
__global__ __launch_bounds__(256) void mamba_kernel(
    const float* __restrict__ u,
    const unsigned short* __restrict__ WinT,
    const float* __restrict__ convw,
    const float* __restrict__ convb,
    const float* __restrict__ dtb,
    const float* __restrict__ Alog,
    const float* __restrict__ Dp,
    const float* __restrict__ normw,
    const unsigned short* __restrict__ WoutT,
    unsigned short* __restrict__ outf)        // (B, 8, 128) bf16
{
    const int tid = threadIdx.x;
    const int lane = tid & 63;
    const int wave = tid >> 6;
    const int l15 = lane & 15;
    const int q8 = (lane >> 4) * 8;
    const int row0 = (lane >> 4) * 4;
    const int grow0 = blockIdx.x * 16;

    __shared__ __align__(16) unsigned short uA[16 * LDK];
    __shared__ __align__(16) unsigned short zx[16 * LDZ];
    __shared__ __align__(16) unsigned short xBC[16 * LDX];
    __shared__ __align__(16) unsigned short yb[16 * LDY];
    __shared__ float dtraw[16][8];
    __shared__ float dtv[2][8][8];
    __shared__ float cum[2][8][8];
    __shared__ float Gm[2][8][8];
    __shared__ float coef[2][8][8][8];
    __shared__ float red[16][16];
    __shared__ float rstd[16];

    for (int i = tid; i < 512; i += 256) {
        int r = i >> 5, k4 = (i & 31) * 4;
        float4 v = *(const float4*)(u + (size_t)(grow0 + r) * DMODEL + k4);
        ushort4 h;
        h.x = f2bf(v.x); h.y = f2bf(v.y); h.z = f2bf(v.z); h.w = f2bf(v.w);
        *(ushort4*)(uA + r * LDK + k4) = h;
    }
    __syncthreads();

    {
        bf16x8 af[4];
        #pragma unroll
        for (int kk = 0; kk < 4; ++kk)
            af[kk] = *(const bf16x8*)(uA + l15 * LDK + kk * 32 + q8);
        for (int nt = wave; nt < 41; nt += 4) {
            floatx4 acc = {0.f, 0.f, 0.f, 0.f};
            const unsigned short* bp = WinT + (size_t)(nt * 16 + l15) * 128 + q8;
            #pragma unroll
            for (int kk = 0; kk < 4; ++kk) {
                bf16x8 bf = *(const bf16x8*)(bp + kk * 32);
                acc = __builtin_amdgcn_mfma_f32_16x16x32_bf16(af[kk], bf, acc, 0, 0, 0);
            }
            if (nt == 40) {
                if (l15 < 8) {
                    #pragma unroll
                    for (int r = 0; r < 4; ++r)
                        dtraw[row0 + r][l15] = acc[r];
                }
            } else {
                #pragma unroll
                for (int r = 0; r < 4; ++r)
                    zx[(row0 + r) * LDZ + nt * 16 + l15] = f2bf(acc[r]);
            }
        }
    }
    __syncthreads();

    for (int i = tid; i < 16 * DCONVCH; i += 256) {
        int r = i / DCONVCH, c = i % DCONVCH;
        int bloc = r >> 3, l = r & 7;
        float s = convb[c];
        #pragma unroll
        for (int k = 0; k < DCONV; ++k) {
            int lp = l + k - (DCONV - 1);
            if (lp >= 0)
                s += bf2f(zx[(bloc * 8 + lp) * LDZ + DINNER + c]) * convw[k * DCONVCH + c];
        }
        xBC[r * LDX + c] = f2bf(siluf(s));
    }
    if (tid < 128) {
        int r = tid >> 3, h = tid & 7;
        float v = dtraw[r][h] + dtb[h];
        dtv[r >> 3][r & 7][h] = (v > 20.f) ? v : log1pf(expf(v));
    }
    __syncthreads();

    if (tid < 128) {
        int bloc = tid >> 6, t = (tid >> 3) & 7, s = tid & 7;
        float a = 0.f;
        for (int n = 0; n < DSTATE; ++n)
            a += bf2f(xBC[(bloc * 8 + s) * LDX + DINNER + n]) *
                 bf2f(xBC[(bloc * 8 + t) * LDX + DINNER + DSTATE + n]);
        Gm[bloc][t][s] = a;
    } else if (tid < 144) {
        int j = tid - 128;
        int bloc = j >> 3, h = j & 7;
        float c = 0.f;
        for (int l = 0; l < L_SEQ; ++l) { c += dtv[bloc][l][h]; cum[bloc][l][h] = c; }
    }
    __syncthreads();

    for (int i = tid; i < 1024; i += 256) {
        int bloc = i >> 9, t = (i >> 6) & 7, s = (i >> 3) & 7, h = i & 7;
        float A = -expf(Alog[h]);
        coef[bloc][t][s][h] = (s <= t)
            ? Gm[bloc][t][s] * expf(A * (cum[bloc][t][h] - cum[bloc][s][h])) * dtv[bloc][s][h]
            : 0.f;
    }
    __syncthreads();

    for (int i = tid; i < 16 * DINNER; i += 256) {
        int r = i >> 8, c = i & 255;
        int bloc = r >> 3, t = r & 7, h = c >> 5;
        float acc = Dp[h] * bf2f(xBC[r * LDX + c]);
        for (int s = 0; s <= t; ++s)
            acc += coef[bloc][t][s][h] * bf2f(xBC[(bloc * 8 + s) * LDX + c]);
        float z = bf2f(zx[r * LDZ + c]);
        yb[r * LDY + c] = f2bf(acc * siluf(z));
    }
    __syncthreads();

    {
        int r = tid >> 4, j = tid & 15;
        float p = 0.f;
        #pragma unroll
        for (int c = j * 16; c < j * 16 + 16; ++c) {
            float v = bf2f(yb[r * LDY + c]);
            p += v * v;
        }
        red[r][j] = p;
    }
    __syncthreads();
    if (tid < 16) {
        float s = 0.f;
        #pragma unroll
        for (int j = 0; j < 16; ++j) s += red[tid][j];
        rstd[tid] = rsqrtf(s / (float)DINNER + 1e-5f);
    }
    __syncthreads();
    for (int i = tid; i < 16 * DINNER; i += 256) {
        int r = i >> 8, c = i & 255;
        yb[r * LDY + c] = f2bf(bf2f(yb[r * LDY + c]) * rstd[r] * normw[c]);
    }
    __syncthreads();

    {
        bf16x8 af[8];
        #pragma unroll
        for (int kk = 0; kk < 8; ++kk)
            af[kk] = *(const bf16x8*)(yb + l15 * LDY + kk * 32 + q8);
        #pragma unroll
        for (int ni = 0; ni < 2; ++ni) {
            int nt = wave * 2 + ni;
            floatx4 acc = {0.f, 0.f, 0.f, 0.f};
            const unsigned short* bp = WoutT + (size_t)(nt * 16 + l15) * 256 + q8;
            #pragma unroll
            for (int kk = 0; kk < 8; ++kk) {
                bf16x8 bf = *(const bf16x8*)(bp + kk * 32);
                acc = __builtin_amdgcn_mfma_f32_16x16x32_bf16(af[kk], bf, acc, 0, 0, 0);
            }
            #pragma unroll
            for (int r = 0; r < 4; ++r)
                outf[(size_t)(grow0 + row0 + r) * DMODEL + nt * 16 + l15] = f2bf(acc[r]);
        }
    }
}

// ---------------------------------------------------------------------------
// Both cross-attentions via MFMA. 2 batches per block (M=16), grid B/2.
// WT: 8 x [128][128] bf16 [n][k]: csQ,csK,csV,csO,cxQ,cxK,cxV,cxO
// pass 0: Q=st_f, KV=exp_f, weights cs_* -> x[..., 0:128]
// pass 1: Q=exp_f, KV=st_f, weights cx_* -> x[..., 128:256]
// ---------------------------------------------------------------------------
#define ASTR 136
#define VSTR 40
#define PSTR 40
__global__ __launch_bounds__(256) void attn_kernel(
    const unsigned short* __restrict__ st_f,   // (B*8,128) bf16
    const unsigned short* __restrict__ exp_f,  // (B*8,128) bf16
    const unsigned short* __restrict__ WT,
    const float* __restrict__ cs_bq, const float* __restrict__ cs_bk,
    const float* __restrict__ cs_bv, const float* __restrict__ cs_bo,
    const float* __restrict__ cx_bq, const float* __restrict__ cx_bk,
    const float* __restrict__ cx_bv, const float* __restrict__ cx_bo,
    __hip_bfloat16* __restrict__ x)            // (B, 2048) bf16
{
    const int tid = threadIdx.x;
    const int lane = tid & 63, wave = tid >> 6;
    const int l15 = lane & 15;
    const int q8 = (lane >> 4) * 8;
    const int row0 = (lane >> 4) * 4;
    const int grow0 = blockIdx.x * 16;
    const int b0 = blockIdx.x * 2;
    const float scale = 0.08838834764831845f;

    __shared__ __align__(16) unsigned short stf[16 * ASTR];
    __shared__ __align__(16) unsigned short exf[16 * ASTR];
    __shared__ __align__(16) unsigned short Qs[16 * ASTR];
    __shared__ __align__(16) unsigned short Ks[16 * ASTR];
    __shared__ __align__(16) unsigned short Vt[128 * VSTR];  // [chan][kvrow], cols 16..31 zero
    __shared__ __align__(16) unsigned short P[16 * PSTR];    // [qrow][kvrow], cols 16..31 zero
    __shared__ __align__(16) unsigned short attv[16 * ASTR];
    __shared__ float Ss[16][17];

    // load features: one uint4 per thread per array
    {
        int r = tid >> 4, c8 = (tid & 15) * 8;
        *(uint4*)(stf + r * ASTR + c8) = *(const uint4*)(st_f + (size_t)(grow0 + r) * 128 + c8);
        *(uint4*)(exf + r * ASTR + c8) = *(const uint4*)(exp_f + (size_t)(grow0 + r) * 128 + c8);
    }
    // zero Vt pad cols 16..31 (once; valid cols rewritten each pass)
    {
        int r = tid >> 1, c = 16 + (tid & 1) * 8;
        uint4 z = {0u, 0u, 0u, 0u};
        *(uint4*)(Vt + r * VSTR + c) = z;
    }
    __syncthreads();

    #pragma unroll
    for (int pass = 0; pass < 2; ++pass) {
        const unsigned short* qsrc = pass ? exf : stf;
        const unsigned short* kvsrc = pass ? stf : exf;
        const unsigned short* Wq = WT + (size_t)pass * 4 * 16384;
        const unsigned short* Wk = Wq + 16384;
        const unsigned short* Wv = Wq + 32768;
        const unsigned short* Wo = Wq + 49152;
        const float* bq = pass ? cx_bq : cs_bq;
        const float* bk = pass ? cx_bk : cs_bk;
        const float* bv = pass ? cx_bv : cs_bv;
        const float* bo = pass ? cx_bo : cs_bo;

        // --- Q/K/V projections ---
        bf16x8 aq[4], akv[4];
        #pragma unroll
        for (int kk = 0; kk < 4; ++kk) {
            aq[kk]  = *(const bf16x8*)(qsrc  + l15 * ASTR + kk * 32 + q8);
            akv[kk] = *(const bf16x8*)(kvsrc + l15 * ASTR + kk * 32 + q8);
        }
        #pragma unroll
        for (int ni = 0; ni < 2; ++ni) {
            int nt = wave * 2 + ni;
            int nc = nt * 16 + l15;
            floatx4 accq = {0.f, 0.f, 0.f, 0.f};
            floatx4 acck = {0.f, 0.f, 0.f, 0.f};
            floatx4 accv = {0.f, 0.f, 0.f, 0.f};
            #pragma unroll
            for (int kk = 0; kk < 4; ++kk) {
                bf16x8 wqf = *(const bf16x8*)(Wq + (size_t)nc * 128 + kk * 32 + q8);
                bf16x8 wkf = *(const bf16x8*)(Wk + (size_t)nc * 128 + kk * 32 + q8);
                bf16x8 wvf = *(const bf16x8*)(Wv + (size_t)nc * 128 + kk * 32 + q8);
                accq = __builtin_amdgcn_mfma_f32_16x16x32_bf16(aq[kk],  wqf, accq, 0, 0, 0);
                acck = __builtin_amdgcn_mfma_f32_16x16x32_bf16(akv[kk], wkf, acck, 0, 0, 0);
                accv = __builtin_amdgcn_mfma_f32_16x16x32_bf16(akv[kk], wvf, accv, 0, 0, 0);
            }
            float bqv = bq[nc], bkv = bk[nc], bvv = bv[nc];
            #pragma unroll
            for (int r = 0; r < 4; ++r) {
                Qs[(row0 + r) * ASTR + nc] = f2bf(accq[r] + bqv);
                Ks[(row0 + r) * ASTR + nc] = f2bf(acck[r] + bkv);
                Vt[nc * VSTR + row0 + r]   = f2bf(accv[r] + bvv);
            }
        }
        __syncthreads();

        // --- scores: S = Q @ K^T (16x16, cross-batch 8x8 blocks invalid) ---
        if (wave == 0) {
            floatx4 s = {0.f, 0.f, 0.f, 0.f};
            #pragma unroll
            for (int kk = 0; kk < 4; ++kk) {
                bf16x8 a = *(const bf16x8*)(Qs + l15 * ASTR + kk * 32 + q8);
                bf16x8 b = *(const bf16x8*)(Ks + l15 * ASTR + kk * 32 + q8);
                s = __builtin_amdgcn_mfma_f32_16x16x32_bf16(a, b, s, 0, 0, 0);
            }
            #pragma unroll
            for (int r = 0; r < 4; ++r) Ss[row0 + r][l15] = s[r];
        }
        __syncthreads();

        // --- softmax rows (valid 8 cols per row) + build padded P ---
        if (tid < 16) {
            int r = tid, c0 = (r >> 3) * 8;
            float v[8], mx = -1e30f;
            #pragma unroll
            for (int c = 0; c < 8; ++c) {
                v[c] = Ss[r][c0 + c] * scale;
                mx = fmaxf(mx, v[c]);
            }
            float sum = 0.f;
            #pragma unroll
            for (int c = 0; c < 8; ++c) { v[c] = expf(v[c] - mx); sum += v[c]; }
            float inv = 1.f / sum;
            #pragma unroll
            for (int c = 0; c < 32; ++c) {
                float pv = (c >= c0 && c < c0 + 8) ? v[c - c0] * inv : 0.f;
                P[r * PSTR + c] = f2bf(pv);
            }
        }
        __syncthreads();

        // --- attV: O = P(16x32) @ V(32x128), Vt[n][k] layout, 1 MFMA/tile ---
        {
            bf16x8 ap = *(const bf16x8*)(P + l15 * PSTR + q8);
            #pragma unroll
            for (int ni = 0; ni < 2; ++ni) {
                int nc = (wave * 2 + ni) * 16 + l15;
                bf16x8 bv_ = *(const bf16x8*)(Vt + nc * VSTR + q8);
                floatx4 o = {0.f, 0.f, 0.f, 0.f};
                o = __builtin_amdgcn_mfma_f32_16x16x32_bf16(ap, bv_, o, 0, 0, 0);
                #pragma unroll
                for (int r = 0; r < 4; ++r)
                    attv[(row0 + r) * ASTR + nc] = f2bf(o[r]);
            }
        }
        __syncthreads();

        // --- Wo projection -> x ---
        {
            bf16x8 ao[4];
            #pragma unroll
            for (int kk = 0; kk < 4; ++kk)
                ao[kk] = *(const bf16x8*)(attv + l15 * ASTR + kk * 32 + q8);
            #pragma unroll
            for (int ni = 0; ni < 2; ++ni) {
                int nc = (wave * 2 + ni) * 16 + l15;
                floatx4 acc = {0.f, 0.f, 0.f, 0.f};
                #pragma unroll
                for (int kk = 0; kk < 4; ++kk) {
                    bf16x8 wof = *(const bf16x8*)(Wo + (size_t)nc * 128 + kk * 32 + q8);
                    acc = __builtin_amdgcn_mfma_f32_16x16x32_bf16(ao[kk], wof, acc, 0, 0, 0);
                }
                float bov = bo[nc];
                #pragma unroll
                for (int r = 0; r < 4; ++r) {
                    int rr = row0 + r;
                    int bb = b0 + (rr >> 3), q = rr & 7;
                    x[(size_t)bb * 2048 + q * 256 + pass * 128 + nc] =
                        __float2bfloat16(acc[r] + bov);
                }
            }
        }
        __syncthreads();
    }
}

// ---------------------------------------------------------------------------
// Tiled transpose+cast for the big MLP weight (unchanged).
// ---------------------------------------------------------------------------
__global__ __launch_bounds__(256) void transpose_w_bf16(
    const float* __restrict__ W, unsigned short* __restrict__ Wt)
{
    __shared__ float tile[32][33];
    const int k0 = blockIdx.y * 32;
    const int n0 = blockIdx.x * 32;
    const int tid = threadIdx.x;
    const int c = tid & 31, r0 = tid >> 5;
    for (int rr = r0; rr < 32; rr += 8)
        tile[rr][c] = W[(k0 + rr) * 1024 + n0 + c];
    __syncthreads();
    for (int rr = r0; rr < 32; rr += 8)
        Wt[(size_t)(n0 + rr) * 2048 + k0 + c] = f2bf(tile[c][rr]);
}

// ---------------------------------------------------------------------------
// MLP via MFMA (unchanged from R2).
// ---------------------------------------------------------------------------
#define LDT 40
__global__ __launch_bounds__(256) void mlp_mfma(
    const unsigned short* __restrict__ X,
    const unsigned short* __restrict__ Wt,
    const float* __restrict__ bias,
    float* __restrict__ out)
{
    __shared__ __align__(16) unsigned short As[64 * LDT];
    __shared__ __align__(16) unsigned short Bs[64 * LDT];
    const int tid = threadIdx.x;
    const int wave = tid >> 6, lane = tid & 63;
    const int wm = (wave >> 1) * 32, wn = (wave & 1) * 32;
    const int bm = blockIdx.y * 64, bn = blockIdx.x * 64;

    const int lrow = tid >> 2;
    const int lcol = (tid & 3) * 8;
    const int l15 = lane & 15;
    const int q8 = (lane >> 4) * 8;

    floatx4 acc00 = {0.f, 0.f, 0.f, 0.f};
    floatx4 acc01 = {0.f, 0.f, 0.f, 0.f};
    floatx4 acc10 = {0.f, 0.f, 0.f, 0.f};
    floatx4 acc11 = {0.f, 0.f, 0.f, 0.f};

    const unsigned short* gA = X + (size_t)(bm + lrow) * 2048 + lcol;
    const unsigned short* gB = Wt + (size_t)(bn + lrow) * 2048 + lcol;

    for (int k0 = 0; k0 < 2048; k0 += 32) {
        uint4 av = *(const uint4*)(gA + k0);
        uint4 bv = *(const uint4*)(gB + k0);
        __syncthreads();
        *(uint4*)(As + lrow * LDT + lcol) = av;
        *(uint4*)(Bs + lrow * LDT + lcol) = bv;
        __syncthreads();
        bf16x8 a0 = *(const bf16x8*)(As + (wm + l15) * LDT + q8);
        bf16x8 a1 = *(const bf16x8*)(As + (wm + 16 + l15) * LDT + q8);
        bf16x8 b0 = *(const bf16x8*)(Bs + (wn + l15) * LDT + q8);
        bf16x8 b1 = *(const bf16x8*)(Bs + (wn + 16 + l15) * LDT + q8);
        acc00 = __builtin_amdgcn_mfma_f32_16x16x32_bf16(a0, b0, acc00, 0, 0, 0);
        acc01 = __builtin_amdgcn_mfma_f32_16x16x32_bf16(a0, b1, acc01, 0, 0, 0);
        acc10 = __builtin_amdgcn_mfma_f32_16x16x32_bf16(a1, b0, acc10, 0, 0, 0);
        acc11 = __builtin_amdgcn_mfma_f32_16x16x32_bf16(a1, b1, acc11, 0, 0, 0);
    }

    const int row0 = (lane >> 4) * 4;
    #pragma unroll
    for (int j = 0; j < 2; ++j) {
        int col = bn + wn + j * 16 + l15;
        float bv = bias[col];
        floatx4 aj0 = j ? acc01 : acc00;
        floatx4 aj1 = j ? acc11 : acc10;
        #pragma unroll
        for (int r = 0; r < 4; ++r) {
            out[(size_t)(bm + wm + row0 + r) * 1024 + col] = aj0[r] + bv;
            out[(size_t)(bm + wm + 16 + row0 + r) * 1024 + col] = aj1[r] + bv;
        }
    }
}

extern "C" void kernel_launch(void* const* d_in, const int* in_sizes, int n_in,
                              void* d_out, int out_size, void* d_ws, size_t ws_size,
                              hipStream_t stream) {
    const float* st_feature = (const float*)d_in[0];
    const float* exp_feature = (const float*)d_in[1];
    const float* st_Win = (const float*)d_in[2];
    const float* st_convw = (const float*)d_in[3];
    const float* st_convb = (const float*)d_in[4];
    const float* st_dtb = (const float*)d_in[5];
    const float* st_Alog = (const float*)d_in[6];
    const float* st_D = (const float*)d_in[7];
    const float* st_normw = (const float*)d_in[8];
    const float* st_Wout = (const float*)d_in[9];
    const float* ex_Win = (const float*)d_in[10];
    const float* ex_convw = (const float*)d_in[11];
    const float* ex_convb = (const float*)d_in[12];
    const float* ex_dtb = (const float*)d_in[13];
    const float* ex_Alog = (const float*)d_in[14];
    const float* ex_D = (const float*)d_in[15];
    const float* ex_normw = (const float*)d_in[16];
    const float* ex_Wout = (const float*)d_in[17];
    const float* cx_Wq = (const float*)d_in[18]; const float* cx_bq = (const float*)d_in[19];
    const float* cx_Wk = (const float*)d_in[20]; const float* cx_bk = (const float*)d_in[21];
    const float* cx_Wv = (const float*)d_in[22]; const float* cx_bv = (const float*)d_in[23];
    const float* cx_Wo = (const float*)d_in[24]; const float* cx_bo = (const float*)d_in[25];
    const float* cs_Wq = (const float*)d_in[26]; const float* cs_bq = (const float*)d_in[27];
    const float* cs_Wk = (const float*)d_in[28]; const float* cs_bk = (const float*)d_in[29];
    const float* cs_Wv = (const float*)d_in[30]; const float* cs_bv = (const float*)d_in[31];
    const float* cs_Wo = (const float*)d_in[32]; const float* cs_bo = (const float*)d_in[33];
    const float* mlp_W = (const float*)d_in[34];
    const float* mlp_b = (const float*)d_in[35];

    unsigned short* wsu = (unsigned short*)d_ws;
    unsigned short* st_fb  = wsu;                               // 2M bf16
    unsigned short* exp_fb = st_fb + (size_t)B_SZ * L_SEQ * DMODEL;
    unsigned short* xbuf   = exp_fb + (size_t)B_SZ * L_SEQ * DMODEL; // 4M bf16
    unsigned short* wtbuf  = xbuf + (size_t)2048 * 2048;        // 2M bf16
    unsigned short* winT_st = wtbuf + (size_t)1024 * 2048;
    unsigned short* winT_ex = winT_st + (size_t)NPAD * 128;
    unsigned short* woutT_st = winT_ex + (size_t)NPAD * 128;
    unsigned short* woutT_ex = woutT_st + (size_t)128 * 256;
    unsigned short* attnWT  = woutT_ex + (size_t)128 * 256;     // 8*16384 bf16

    transpose_cast<<<(NPAD * 128 + 255) / 256, 256, 0, stream>>>(st_Win, winT_st, 128, DINPROJ, NPAD);
    transpose_cast<<<(NPAD * 128 + 255) / 256, 256, 0, stream>>>(ex_Win, winT_ex, 128, DINPROJ, NPAD);
    transpose_cast<<<(128 * 256 + 255) / 256, 256, 0, stream>>>(st_Wout, woutT_st, 256, 128, 128);
    transpose_cast<<<(128 * 256 + 255) / 256, 256, 0, stream>>>(ex_Wout, woutT_ex, 256, 128, 128);
    transpose_attn_w<<<512, 256, 0, stream>>>(cs_Wq, cs_Wk, cs_Wv, cs_Wo,
                                              cx_Wq, cx_Wk, cx_Wv, cx_Wo, attnWT);
    {
        dim3 g(1024 / 32, 2048 / 32);
        transpose_w_bf16<<<g, 256, 0, stream>>>(mlp_W, wtbuf);
    }

    mamba_kernel<<<B_SZ / 2, 256, 0, stream>>>(exp_feature, winT_ex, ex_convw, ex_convb,
                                               ex_dtb, ex_Alog, ex_D, ex_normw, woutT_ex, exp_fb);
    mamba_kernel<<<B_SZ / 2, 256, 0, stream>>>(st_feature, winT_st, st_convw, st_convb,
                                               st_dtb, st_Alog, st_D, st_normw, woutT_st, st_fb);
    attn_kernel<<<B_SZ / 2, 256, 0, stream>>>(st_fb, exp_fb, attnWT,
                                              cs_bq, cs_bk, cs_bv, cs_bo,
                                              cx_bq, cx_bk, cx_bv, cx_bo,
                                              (__hip_bfloat16*)xbuf);
    {
        dim3 g(1024 / 64, 2048 / 64);
        mlp_mfma<<<g, 256, 0, stream>>>(xbuf, wtbuf, mlp_b, (float*)d_out);
    }
}

// Round 5
// 273.651 us; speedup vs baseline: 3.1255x; 1.2287x over previous
//
#include <hip/hip_runtime.h>
#include <hip/hip_bf16.h>
#include <math.h>

#define B_SZ 2048
#define L_SEQ 8
#define DMODEL 128
#define DSTATE 64
#define HEADDIM 32
#define DCONV 4
#define DINNER 256
#define NHEADS 8
#define DCONVCH 384   // DINNER + 2*DSTATE
#define DINPROJ 648   // 2*DINNER + 2*DSTATE + NHEADS
#define NPAD 656      // 41 * 16

typedef short bf16x8 __attribute__((ext_vector_type(8)));
typedef float floatx4 __attribute__((ext_vector_type(4)));

__device__ __forceinline__ float siluf(float x) {
    return x / (1.f + expf(-x));
}
__device__ __forceinline__ float bf2f(unsigned short h) {
    unsigned int u = ((unsigned int)h) << 16;
    return __builtin_bit_cast(float, u);
}
__device__ __forceinline__ unsigned short f2bf(float f) {
    __hip_bfloat16 b = __float2bfloat16(f);
    return __builtin_bit_cast(unsigned short, b);
}
__device__ __forceinline__ void unpack8(bf16x8 v, float* o) {
    #pragma unroll
    for (int j = 0; j < 8; ++j) o[j] = bf2f((unsigned short)v[j]);
}

// ---------------------------------------------------------------------------
// One merged prep kernel: all small weight transposes+casts.
// blocks 0..327     : st_Win  -> winT_st  (656x128)
// blocks 328..655   : ex_Win  -> winT_ex
// blocks 656..783   : st_Wout -> woutT_st (128x256)
// blocks 784..911   : ex_Wout -> woutT_ex
// blocks 912..1423  : 8 attn 128x128 mats -> attnWT
// ---------------------------------------------------------------------------
__global__ __launch_bounds__(256) void prep_weights(
    const float* __restrict__ st_Win, const float* __restrict__ ex_Win,
    const float* __restrict__ st_Wout, const float* __restrict__ ex_Wout,
    const float* __restrict__ cs_Wq, const float* __restrict__ cs_Wk,
    const float* __restrict__ cs_Wv, const float* __restrict__ cs_Wo,
    const float* __restrict__ cx_Wq, const float* __restrict__ cx_Wk,
    const float* __restrict__ cx_Wv, const float* __restrict__ cx_Wo,
    unsigned short* __restrict__ winT_st, unsigned short* __restrict__ winT_ex,
    unsigned short* __restrict__ woutT_st, unsigned short* __restrict__ woutT_ex,
    unsigned short* __restrict__ attnWT)
{
    int blk = blockIdx.x;
    if (blk < 656) {
        const float* src = blk < 328 ? st_Win : ex_Win;
        unsigned short* dst = blk < 328 ? winT_st : winT_ex;
        int idx = (blk % 328) * 256 + threadIdx.x;
        if (idx >= NPAD * 128) return;
        int n = idx / 128, k = idx % 128;
        float v = (n < DINPROJ) ? src[k * DINPROJ + n] : 0.f;
        dst[idx] = f2bf(v);
    } else if (blk < 912) {
        const float* src = blk < 784 ? st_Wout : ex_Wout;
        unsigned short* dst = blk < 784 ? woutT_st : woutT_ex;
        int idx = ((blk - 656) % 128) * 256 + threadIdx.x;
        int n = idx / 256, k = idx % 256;   // dst [128][256]
        dst[idx] = f2bf(src[k * 128 + n]);
    } else {
        int b2 = blk - 912;
        int mat = b2 >> 6;
        const float* src = mat == 0 ? cs_Wq : mat == 1 ? cs_Wk : mat == 2 ? cs_Wv :
                           mat == 3 ? cs_Wo : mat == 4 ? cx_Wq : mat == 5 ? cx_Wk :
                           mat == 6 ? cx_Wv : cx_Wo;
        int e = (b2 & 63) * 256 + threadIdx.x;
        int n = e >> 7, k = e & 127;
        attnWT[mat * 16384 + n * 128 + k] = f2bf(src[k * 128 + n]);
    }
}

// ---------------------------------------------------------------------------
// Dual Mamba2: 2048 blocks; block 0..1023 = exp params, 1024..2047 = st.
// 2 batches per block (M=16). LDS ~37.7 KB -> 4 blocks/CU.
// Conv writes back in place into zx; coef overlays dead uA.
// All bulk LDS phases use bf16x8 (b128) access.
// ---------------------------------------------------------------------------
#define LDK 136
#define LDZ 648
#define LDY 264
__global__ __launch_bounds__(256, 4) void mamba_dual(
    const float* __restrict__ u_ex, const float* __restrict__ u_st,
    const unsigned short* __restrict__ WinT_ex, const unsigned short* __restrict__ WinT_st,
    const float* __restrict__ convw_ex, const float* __restrict__ convw_st,
    const float* __restrict__ convb_ex, const float* __restrict__ convb_st,
    const float* __restrict__ dtb_ex, const float* __restrict__ dtb_st,
    const float* __restrict__ Alog_ex, const float* __restrict__ Alog_st,
    const float* __restrict__ Dp_ex, const float* __restrict__ Dp_st,
    const float* __restrict__ normw_ex, const float* __restrict__ normw_st,
    const unsigned short* __restrict__ WoutT_ex, const unsigned short* __restrict__ WoutT_st,
    unsigned short* __restrict__ out_ex, unsigned short* __restrict__ out_st)
{
    const int which = blockIdx.x >> 10;        // 0 = exp, 1 = st
    const float* u = which ? u_st : u_ex;
    const unsigned short* WinT = which ? WinT_st : WinT_ex;
    const float* convw = which ? convw_st : convw_ex;
    const float* convb = which ? convb_st : convb_ex;
    const float* dtb = which ? dtb_st : dtb_ex;
    const float* Alog = which ? Alog_st : Alog_ex;
    const float* Dp = which ? Dp_st : Dp_ex;
    const float* normw = which ? normw_st : normw_ex;
    const unsigned short* WoutT = which ? WoutT_st : WoutT_ex;
    unsigned short* outf = which ? out_st : out_ex;

    const int tid = threadIdx.x;
    const int lane = tid & 63;
    const int wave = tid >> 6;
    const int l15 = lane & 15;
    const int q8 = (lane >> 4) * 8;
    const int row0 = (lane >> 4) * 4;
    const int grow0 = (blockIdx.x & 1023) * 16;

    __shared__ __align__(16) unsigned short uA[16 * LDK];   // 4352 B; coef overlays
    __shared__ __align__(16) unsigned short zx[16 * LDZ];   // 20736 B
    __shared__ __align__(16) unsigned short yb[16 * LDY];   // 8448 B
    __shared__ float dtraw[16][8];
    __shared__ float dtv[2][8][8];
    __shared__ float cum[2][8][8];
    __shared__ float Gm[2][8][8];
    __shared__ float red[16][32];
    __shared__ float rstd[16];
    float* coefp = (float*)uA;   // [2][8][8][8] = 4096 B, overlays dead uA

    // --- phase 1: load u -> bf16 A-tile ---
    for (int i = tid; i < 512; i += 256) {
        int r = i >> 5, k4 = (i & 31) * 4;
        float4 v = *(const float4*)(u + (size_t)(grow0 + r) * DMODEL + k4);
        ushort4 h;
        h.x = f2bf(v.x); h.y = f2bf(v.y); h.z = f2bf(v.z); h.w = f2bf(v.w);
        *(ushort4*)(uA + r * LDK + k4) = h;
    }
    __syncthreads();

    // --- phase 2: in_proj MFMA: zx[16][640] + dtraw ---
    {
        bf16x8 af[4];
        #pragma unroll
        for (int kk = 0; kk < 4; ++kk)
            af[kk] = *(const bf16x8*)(uA + l15 * LDK + kk * 32 + q8);
        for (int nt = wave; nt < 41; nt += 4) {
            floatx4 acc = {0.f, 0.f, 0.f, 0.f};
            const unsigned short* bp = WinT + (size_t)(nt * 16 + l15) * 128 + q8;
            #pragma unroll
            for (int kk = 0; kk < 4; ++kk) {
                bf16x8 bf = *(const bf16x8*)(bp + kk * 32);
                acc = __builtin_amdgcn_mfma_f32_16x16x32_bf16(af[kk], bf, acc, 0, 0, 0);
            }
            if (nt == 40) {
                if (l15 < 8) {
                    #pragma unroll
                    for (int r = 0; r < 4; ++r)
                        dtraw[row0 + r][l15] = acc[r];
                }
            } else {
                #pragma unroll
                for (int r = 0; r < 4; ++r)
                    zx[(row0 + r) * LDZ + nt * 16 + l15] = f2bf(acc[r]);
            }
        }
    }
    __syncthreads();

    // --- phase 3: conv+silu into registers (in-place rewrite of zx[256..639]),
    //     + dt softplus. 768 items of 8 channels; 3 per thread. ---
    float cv[3][8];
    {
        #pragma unroll
        for (int it = 0; it < 3; ++it) {
            int i = tid + it * 256;
            int r = i / 48, g = i % 48;
            int c0 = g * 8;                  // xBC channel base
            int l = r & 7, bloc = r >> 3;
            float s[8];
            float4 cb0 = *(const float4*)(convb + c0);
            float4 cb1 = *(const float4*)(convb + c0 + 4);
            s[0] = cb0.x; s[1] = cb0.y; s[2] = cb0.z; s[3] = cb0.w;
            s[4] = cb1.x; s[5] = cb1.y; s[6] = cb1.z; s[7] = cb1.w;
            #pragma unroll
            for (int k = 0; k < DCONV; ++k) {
                int lp = l + k - (DCONV - 1);
                if (lp >= 0) {
                    bf16x8 v = *(const bf16x8*)(zx + (bloc * 8 + lp) * LDZ + 256 + c0);
                    float vf[8];
                    unpack8(v, vf);
                    float4 w0 = *(const float4*)(convw + k * DCONVCH + c0);
                    float4 w1 = *(const float4*)(convw + k * DCONVCH + c0 + 4);
                    s[0] += vf[0] * w0.x; s[1] += vf[1] * w0.y;
                    s[2] += vf[2] * w0.z; s[3] += vf[3] * w0.w;
                    s[4] += vf[4] * w1.x; s[5] += vf[5] * w1.y;
                    s[6] += vf[6] * w1.z; s[7] += vf[7] * w1.w;
                }
            }
            #pragma unroll
            for (int j = 0; j < 8; ++j) cv[it][j] = siluf(s[j]);
        }
        if (tid < 128) {
            int r = tid >> 3, h = tid & 7;
            float v = dtraw[r][h] + dtb[h];
            dtv[r >> 3][r & 7][h] = (v > 20.f) ? v : log1pf(expf(v));
        }
    }
    __syncthreads();
    {
        #pragma unroll
        for (int it = 0; it < 3; ++it) {
            int i = tid + it * 256;
            int r = i / 48, c0 = (i % 48) * 8;
            bf16x8 o;
            #pragma unroll
            for (int j = 0; j < 8; ++j) o[j] = (short)f2bf(cv[it][j]);
            *(bf16x8*)(zx + r * LDZ + 256 + c0) = o;
        }
    }
    __syncthreads();

    // --- phase 5: Gm (vectorized) + cum ---
    if (tid < 128) {
        int bloc = tid >> 6, t = (tid >> 3) & 7, s = tid & 7;
        float a = 0.f;
        #pragma unroll
        for (int n = 0; n < DSTATE; n += 8) {
            bf16x8 bv = *(const bf16x8*)(zx + (bloc * 8 + s) * LDZ + 512 + n);
            bf16x8 cvv = *(const bf16x8*)(zx + (bloc * 8 + t) * LDZ + 576 + n);
            float bf_[8], cf_[8];
            unpack8(bv, bf_); unpack8(cvv, cf_);
            #pragma unroll
            for (int j = 0; j < 8; ++j) a += bf_[j] * cf_[j];
        }
        Gm[bloc][t][s] = a;
    } else if (tid < 144) {
        int j = tid - 128;
        int bloc = j >> 3, h = j & 7;
        float c = 0.f;
        for (int l = 0; l < L_SEQ; ++l) { c += dtv[bloc][l][h]; cum[bloc][l][h] = c; }
    }
    __syncthreads();

    // --- phase 6: coef (overlaid on uA) ---
    for (int i = tid; i < 1024; i += 256) {
        int bloc = i >> 9, t = (i >> 6) & 7, s = (i >> 3) & 7, h = i & 7;
        float A = -expf(Alog[h]);
        coefp[i] = (s <= t)
            ? Gm[bloc][t][s] * expf(A * (cum[bloc][t][h] - cum[bloc][s][h])) * dtv[bloc][s][h]
            : 0.f;
    }
    __syncthreads();

    // --- phase 7: scan + gate + partial sumsq (vectorized, 2 items/thread) ---
    {
        #pragma unroll
        for (int it = 0; it < 2; ++it) {
            int i = tid + it * 256;
            int r = i >> 5, g = i & 31;
            int c0 = g * 8, h = g >> 2;
            int bloc = r >> 3, t = r & 7;
            float acc[8];
            {
                bf16x8 xv = *(const bf16x8*)(zx + r * LDZ + 256 + c0);
                float xf[8]; unpack8(xv, xf);
                float d = Dp[h];
                #pragma unroll
                for (int j = 0; j < 8; ++j) acc[j] = d * xf[j];
            }
            for (int s = 0; s <= t; ++s) {
                float cf = coefp[((bloc * 8 + t) * 8 + s) * 8 + h];
                bf16x8 xv = *(const bf16x8*)(zx + (bloc * 8 + s) * LDZ + 256 + c0);
                float xf[8]; unpack8(xv, xf);
                #pragma unroll
                for (int j = 0; j < 8; ++j) acc[j] += cf * xf[j];
            }
            bf16x8 zv = *(const bf16x8*)(zx + r * LDZ + c0);
            float zf[8]; unpack8(zv, zf);
            float p = 0.f;
            bf16x8 o;
            #pragma unroll
            for (int j = 0; j < 8; ++j) {
                float y = acc[j] * siluf(zf[j]);
                p += y * y;
                o[j] = (short)f2bf(y);
            }
            *(bf16x8*)(yb + r * LDY + c0) = o;
            red[r][g] = p;
        }
    }
    __syncthreads();
    if (tid < 16) {
        float s = 0.f;
        #pragma unroll
        for (int j = 0; j < 32; ++j) s += red[tid][j];
        rstd[tid] = rsqrtf(s / (float)DINNER + 1e-5f);
    }
    __syncthreads();
    // --- rmsnorm scale (vectorized) ---
    {
        #pragma unroll
        for (int it = 0; it < 2; ++it) {
            int i = tid + it * 256;
            int r = i >> 5, c0 = (i & 31) * 8;
            bf16x8 v = *(const bf16x8*)(yb + r * LDY + c0);
            float vf[8]; unpack8(v, vf);
            float4 w0 = *(const float4*)(normw + c0);
            float4 w1 = *(const float4*)(normw + c0 + 4);
            float rs = rstd[r];
            bf16x8 o;
            o[0] = (short)f2bf(vf[0] * rs * w0.x); o[1] = (short)f2bf(vf[1] * rs * w0.y);
            o[2] = (short)f2bf(vf[2] * rs * w0.z); o[3] = (short)f2bf(vf[3] * rs * w0.w);
            o[4] = (short)f2bf(vf[4] * rs * w1.x); o[5] = (short)f2bf(vf[5] * rs * w1.y);
            o[6] = (short)f2bf(vf[6] * rs * w1.z); o[7] = (short)f2bf(vf[7] * rs * w1.w);
            *(bf16x8*)(yb + r * LDY + c0) = o;
        }
    }
    __syncthreads();

    // --- phase 9: out_proj MFMA ---
    {
        bf16x8 af[8];
        #pragma unroll
        for (int kk = 0; kk < 8; ++kk)
            af[kk] = *(const bf16x8*)(yb + l15 * LDY + kk * 32 + q8);
        #pragma unroll
        for (int ni = 0; ni < 2; ++ni) {
            int nt = wave * 2 + ni;
            floatx4 acc = {0.f, 0.f, 0.f, 0.f};
            const unsigned short* bp = WoutT + (size_t)(nt * 16 + l15) * 256 + q8;
            #pragma unroll
            for (int kk = 0; kk < 8; ++kk) {
                bf16x8 bf = *(const bf16x8*)(bp + kk * 32);
                acc = __builtin_amdgcn_mfma_f32_16x16x32_bf16(af[kk], bf, acc, 0, 0, 0);
            }
            #pragma unroll
            for (int r = 0; r < 4; ++r)
                outf[(size_t)(grow0 + row0 + r) * DMODEL + nt * 16 + l15] = f2bf(acc[r]);
        }
    }
}

// ---------------------------------------------------------------------------
// Both cross-attentions via MFMA (unchanged from R4).
// ---------------------------------------------------------------------------
#define ASTR 136
#define VSTR 40
#define PSTR 40
__global__ __launch_bounds__(256) void attn_kernel(
    const unsigned short* __restrict__ st_f,
    const unsigned short* __restrict__ exp_f,
    const unsigned short* __restrict__ WT,
    const float* __restrict__ cs_bq, const float* __restrict__ cs_bk,
    const float* __restrict__ cs_bv, const float* __restrict__ cs_bo,
    const float* __restrict__ cx_bq, const float* __restrict__ cx_bk,
    const float* __restrict__ cx_bv, const float* __restrict__ cx_bo,
    __hip_bfloat16* __restrict__ x)
{
    const int tid = threadIdx.x;
    const int lane = tid & 63, wave = tid >> 6;
    const int l15 = lane & 15;
    const int q8 = (lane >> 4) * 8;
    const int row0 = (lane >> 4) * 4;
    const int grow0 = blockIdx.x * 16;
    const int b0 = blockIdx.x * 2;
    const float scale = 0.08838834764831845f;

    __shared__ __align__(16) unsigned short stf[16 * ASTR];
    __shared__ __align__(16) unsigned short exf[16 * ASTR];
    __shared__ __align__(16) unsigned short Qs[16 * ASTR];
    __shared__ __align__(16) unsigned short Ks[16 * ASTR];
    __shared__ __align__(16) unsigned short Vt[128 * VSTR];
    __shared__ __align__(16) unsigned short P[16 * PSTR];
    __shared__ __align__(16) unsigned short attv[16 * ASTR];
    __shared__ float Ss[16][17];

    {
        int r = tid >> 4, c8 = (tid & 15) * 8;
        *(uint4*)(stf + r * ASTR + c8) = *(const uint4*)(st_f + (size_t)(grow0 + r) * 128 + c8);
        *(uint4*)(exf + r * ASTR + c8) = *(const uint4*)(exp_f + (size_t)(grow0 + r) * 128 + c8);
    }
    {
        int r = tid >> 1, c = 16 + (tid & 1) * 8;
        uint4 z = {0u, 0u, 0u, 0u};
        *(uint4*)(Vt + r * VSTR + c) = z;
    }
    __syncthreads();

    #pragma unroll
    for (int pass = 0; pass < 2; ++pass) {
        const unsigned short* qsrc = pass ? exf : stf;
        const unsigned short* kvsrc = pass ? stf : exf;
        const unsigned short* Wq = WT + (size_t)pass * 4 * 16384;
        const unsigned short* Wk = Wq + 16384;
        const unsigned short* Wv = Wq + 32768;
        const unsigned short* Wo = Wq + 49152;
        const float* bq = pass ? cx_bq : cs_bq;
        const float* bk = pass ? cx_bk : cs_bk;
        const float* bv = pass ? cx_bv : cs_bv;
        const float* bo = pass ? cx_bo : cs_bo;

        bf16x8 aq[4], akv[4];
        #pragma unroll
        for (int kk = 0; kk < 4; ++kk) {
            aq[kk]  = *(const bf16x8*)(qsrc  + l15 * ASTR + kk * 32 + q8);
            akv[kk] = *(const bf16x8*)(kvsrc + l15 * ASTR + kk * 32 + q8);
        }
        #pragma unroll
        for (int ni = 0; ni < 2; ++ni) {
            int nt = wave * 2 + ni;
            int nc = nt * 16 + l15;
            floatx4 accq = {0.f, 0.f, 0.f, 0.f};
            floatx4 acck = {0.f, 0.f, 0.f, 0.f};
            floatx4 accv = {0.f, 0.f, 0.f, 0.f};
            #pragma unroll
            for (int kk = 0; kk < 4; ++kk) {
                bf16x8 wqf = *(const bf16x8*)(Wq + (size_t)nc * 128 + kk * 32 + q8);
                bf16x8 wkf = *(const bf16x8*)(Wk + (size_t)nc * 128 + kk * 32 + q8);
                bf16x8 wvf = *(const bf16x8*)(Wv + (size_t)nc * 128 + kk * 32 + q8);
                accq = __builtin_amdgcn_mfma_f32_16x16x32_bf16(aq[kk],  wqf, accq, 0, 0, 0);
                acck = __builtin_amdgcn_mfma_f32_16x16x32_bf16(akv[kk], wkf, acck, 0, 0, 0);
                accv = __builtin_amdgcn_mfma_f32_16x16x32_bf16(akv[kk], wvf, accv, 0, 0, 0);
            }
            float bqv = bq[nc], bkv = bk[nc], bvv = bv[nc];
            #pragma unroll
            for (int r = 0; r < 4; ++r) {
                Qs[(row0 + r) * ASTR + nc] = f2bf(accq[r] + bqv);
                Ks[(row0 + r) * ASTR + nc] = f2bf(acck[r] + bkv);
                Vt[nc * VSTR + row0 + r]   = f2bf(accv[r] + bvv);
            }
        }
        __syncthreads();

        if (wave == 0) {
            floatx4 s = {0.f, 0.f, 0.f, 0.f};
            #pragma unroll
            for (int kk = 0; kk < 4; ++kk) {
                bf16x8 a = *(const bf16x8*)(Qs + l15 * ASTR + kk * 32 + q8);
                bf16x8 b = *(const bf16x8*)(Ks + l15 * ASTR + kk * 32 + q8);
                s = __builtin_amdgcn_mfma_f32_16x16x32_bf16(a, b, s, 0, 0, 0);
            }
            #pragma unroll
            for (int r = 0; r < 4; ++r) Ss[row0 + r][l15] = s[r];
        }
        __syncthreads();

        if (tid < 16) {
            int r = tid, c0 = (r >> 3) * 8;
            float v[8], mx = -1e30f;
            #pragma unroll
            for (int c = 0; c < 8; ++c) {
                v[c] = Ss[r][c0 + c] * scale;
                mx = fmaxf(mx, v[c]);
            }
            float sum = 0.f;
            #pragma unroll
            for (int c = 0; c < 8; ++c) { v[c] = expf(v[c] - mx); sum += v[c]; }
            float inv = 1.f / sum;
            #pragma unroll
            for (int c = 0; c < 32; ++c) {
                float pv = (c >= c0 && c < c0 + 8) ? v[c - c0] * inv : 0.f;
                P[r * PSTR + c] = f2bf(pv);
            }
        }
        __syncthreads();

        {
            bf16x8 ap = *(const bf16x8*)(P + l15 * PSTR + q8);
            #pragma unroll
            for (int ni = 0; ni < 2; ++ni) {
                int nc = (wave * 2 + ni) * 16 + l15;
                bf16x8 bv_ = *(const bf16x8*)(Vt + nc * VSTR + q8);
                floatx4 o = {0.f, 0.f, 0.f, 0.f};
                o = __builtin_amdgcn_mfma_f32_16x16x32_bf16(ap, bv_, o, 0, 0, 0);
                #pragma unroll
                for (int r = 0; r < 4; ++r)
                    attv[(row0 + r) * ASTR + nc] = f2bf(o[r]);
            }
        }
        __syncthreads();

        {
            bf16x8 ao[4];
            #pragma unroll
            for (int kk = 0; kk < 4; ++kk)
                ao[kk] = *(const bf16x8*)(attv + l15 * ASTR + kk * 32 + q8);
            #pragma unroll
            for (int ni = 0; ni < 2; ++ni) {
                int nc = (wave * 2 + ni) * 16 + l15;
                floatx4 acc = {0.f, 0.f, 0.f, 0.f};
                #pragma unroll
                for (int kk = 0; kk < 4; ++kk) {
                    bf16x8 wof = *(const bf16x8*)(Wo + (size_t)nc * 128 + kk * 32 + q8);
                    acc = __builtin_amdgcn_mfma_f32_16x16x32_bf16(ao[kk], wof, acc, 0, 0, 0);
                }
                float bov = bo[nc];
                #pragma unroll
                for (int r = 0; r < 4; ++r) {
                    int rr = row0 + r;
                    int bb = b0 + (rr >> 3), q = rr & 7;
                    x[(size_t)bb * 2048 + q * 256 + pass * 128 + nc] =
                        __float2bfloat16(acc[r] + bov);
                }
            }
        }
        __syncthreads();
    }
}

// ---------------------------------------------------------------------------
// Tiled transpose+cast for the big MLP weight (unchanged).
// ---------------------------------------------------------------------------
__global__ __launch_bounds__(256) void transpose_w_bf16(
    const float* __restrict__ W, unsigned short* __restrict__ Wt)
{
    __shared__ float tile[32][33];
    const int k0 = blockIdx.y * 32;
    const int n0 = blockIdx.x * 32;
    const int tid = threadIdx.x;
    const int c = tid & 31, r0 = tid >> 5;
    for (int rr = r0; rr < 32; rr += 8)
        tile[rr][c] = W[(k0 + rr) * 1024 + n0 + c];
    __syncthreads();
    for (int rr = r0; rr < 32; rr += 8)
        Wt[(size_t)(n0 + rr) * 2048 + k0 + c] = f2bf(tile[c][rr]);
}

// ---------------------------------------------------------------------------
// MLP via MFMA (unchanged).
// ---------------------------------------------------------------------------
#define LDT 40
__global__ __launch_bounds__(256) void mlp_mfma(
    const unsigned short* __restrict__ X,
    const unsigned short* __restrict__ Wt,
    const float* __restrict__ bias,
    float* __restrict__ out)
{
    __shared__ __align__(16) unsigned short As[64 * LDT];
    __shared__ __align__(16) unsigned short Bs[64 * LDT];
    const int tid = threadIdx.x;
    const int wave = tid >> 6, lane = tid & 63;
    const int wm = (wave >> 1) * 32, wn = (wave & 1) * 32;
    const int bm = blockIdx.y * 64, bn = blockIdx.x * 64;

    const int lrow = tid >> 2;
    const int lcol = (tid & 3) * 8;
    const int l15 = lane & 15;
    const int q8 = (lane >> 4) * 8;

    floatx4 acc00 = {0.f, 0.f, 0.f, 0.f};
    floatx4 acc01 = {0.f, 0.f, 0.f, 0.f};
    floatx4 acc10 = {0.f, 0.f, 0.f, 0.f};
    floatx4 acc11 = {0.f, 0.f, 0.f, 0.f};

    const unsigned short* gA = X + (size_t)(bm + lrow) * 2048 + lcol;
    const unsigned short* gB = Wt + (size_t)(bn + lrow) * 2048 + lcol;

    for (int k0 = 0; k0 < 2048; k0 += 32) {
        uint4 av = *(const uint4*)(gA + k0);
        uint4 bv = *(const uint4*)(gB + k0);
        __syncthreads();
        *(uint4*)(As + lrow * LDT + lcol) = av;
        *(uint4*)(Bs + lrow * LDT + lcol) = bv;
        __syncthreads();
        bf16x8 a0 = *(const bf16x8*)(As + (wm + l15) * LDT + q8);
        bf16x8 a1 = *(const bf16x8*)(As + (wm + 16 + l15) * LDT + q8);
        bf16x8 b0 = *(const bf16x8*)(Bs + (wn + l15) * LDT + q8);
        bf16x8 b1 = *(const bf16x8*)(Bs + (wn + 16 + l15) * LDT + q8);
        acc00 = __builtin_amdgcn_mfma_f32_16x16x32_bf16(a0, b0, acc00, 0, 0, 0);
        acc01 = __builtin_amdgcn_mfma_f32_16x16x32_bf16(a0, b1, acc01, 0, 0, 0);
        acc10 = __builtin_amdgcn_mfma_f32_16x16x32_bf16(a1, b0, acc10, 0, 0, 0);
        acc11 = __builtin_amdgcn_mfma_f32_16x16x32_bf16(a1, b1, acc11, 0, 0, 0);
    }

    const int row0 = (lane >> 4) * 4;
    #pragma unroll
    for (int j = 0; j < 2; ++j) {
        int col = bn + wn + j * 16 + l15;
        float bv = bias[col];
        floatx4 aj0 = j ? acc01 : acc00;
        floatx4 aj1 = j ? acc11 : acc10;
        #pragma unroll
        for (int r = 0; r < 4; ++r) {
            out[(size_t)(bm + wm + row0 + r) * 1024 + col] = aj0[r] + bv;
            out[(size_t)(bm + wm + 16 + row0 + r) * 1024 + col] = aj1[r] + bv;
        }
    }
}

extern "C" void kernel_launch(void* const* d_in, const int* in_sizes, int n_in,
                              void* d_out, int out_size, void* d_ws, size_t ws_size,
                              hipStream_t stream) {
    const float* st_feature = (const float*)d_in[0];
    const float* exp_feature = (const float*)d_in[1];
    const float* st_Win = (const float*)d_in[2];
    const float* st_convw = (const float*)d_in[3];
    const float* st_convb = (const float*)d_in[4];
    const float* st_dtb = (const float*)d_in[5];
    const float* st_Alog = (const float*)d_in[6];
    const float* st_D = (const float*)d_in[7];
    const float* st_normw = (const float*)d_in[8];
    const float* st_Wout = (const float*)d_in[9];
    const float* ex_Win = (const float*)d_in[10];
    const float* ex_convw = (const float*)d_in[11];
    const float* ex_convb = (const float*)d_in[12];
    const float* ex_dtb = (const float*)d_in[13];
    const float* ex_Alog = (const float*)d_in[14];
    const float* ex_D = (const float*)d_in[15];
    const float* ex_normw = (const float*)d_in[16];
    const float* ex_Wout = (const float*)d_in[17];
    const float* cx_Wq = (const float*)d_in[18]; const float* cx_bq = (const float*)d_in[19];
    const float* cx_Wk = (const float*)d_in[20]; const float* cx_bk = (const float*)d_in[21];
    const float* cx_Wv = (const float*)d_in[22]; const float* cx_bv = (const float*)d_in[23];
    const float* cx_Wo = (const float*)d_in[24]; const float* cx_bo = (const float*)d_in[25];
    const float* cs_Wq = (const float*)d_in[26]; const float* cs_bq = (const float*)d_in[27];
    const float* cs_Wk = (const float*)d_in[28]; const float* cs_bk = (const float*)d_in[29];
    const float* cs_Wv = (const float*)d_in[30]; const float* cs_bv = (const float*)d_in[31];
    const float* cs_Wo = (const float*)d_in[32]; const float* cs_bo = (const float*)d_in[33];
    const float* mlp_W = (const float*)d_in[34];
    const float* mlp_b = (const float*)d_in[35];

    unsigned short* wsu = (unsigned short*)d_ws;
    unsigned short* st_fb  = wsu;
    unsigned short* exp_fb = st_fb + (size_t)B_SZ * L_SEQ * DMODEL;
    unsigned short* xbuf   = exp_fb + (size_t)B_SZ * L_SEQ * DMODEL;
    unsigned short* wtbuf  = xbuf + (size_t)2048 * 2048;
    unsigned short* winT_st = wtbuf + (size_t)1024 * 2048;
    unsigned short* winT_ex = winT_st + (size_t)NPAD * 128;
    unsigned short* woutT_st = winT_ex + (size_t)NPAD * 128;
    unsigned short* woutT_ex = woutT_st + (size_t)128 * 256;
    unsigned short* attnWT  = woutT_ex + (size_t)128 * 256;

    prep_weights<<<1424, 256, 0, stream>>>(
        st_Win, ex_Win, st_Wout, ex_Wout,
        cs_Wq, cs_Wk, cs_Wv, cs_Wo, cx_Wq, cx_Wk, cx_Wv, cx_Wo,
        winT_st, winT_ex, woutT_st, woutT_ex, attnWT);
    {
        dim3 g(1024 / 32, 2048 / 32);
        transpose_w_bf16<<<g, 256, 0, stream>>>(mlp_W, wtbuf);
    }
    mamba_dual<<<2048, 256, 0, stream>>>(
        exp_feature, st_feature, winT_ex, winT_st,
        ex_convw, st_convw, ex_convb, st_convb,
        ex_dtb, st_dtb, ex_Alog, st_Alog, ex_D, st_D,
        ex_normw, st_normw, woutT_ex, woutT_st,
        exp_fb, st_fb);
    attn_kernel<<<B_SZ / 2, 256, 0, stream>>>(st_fb, exp_fb, attnWT,
                                              cs_bq, cs_bk, cs_bv, cs_bo,
                                              cx_bq, cx_bk, cx_bv, cx_bo,
                                              (__hip_bfloat16*)xbuf);
    {
        dim3 g(1024 / 64, 2048 / 64);
        mlp_mfma<<<g, 256, 0, stream>>>(xbuf, wtbuf, mlp_b, (float*)d_out);
    }
}

// Round 6
// 253.540 us; speedup vs baseline: 3.3734x; 1.0793x over previous
//
#include <hip/hip_runtime.h>
#include <hip/hip_bf16.h>
#include <math.h>

#define B_SZ 2048
#define L_SEQ 8
#define DMODEL 128
#define DSTATE 64
#define HEADDIM 32
#define DCONV 4
#define DINNER 256
#define NHEADS 8
#define DCONVCH 384   // DINNER + 2*DSTATE
#define DINPROJ 648   // 2*DINNER + 2*DSTATE + NHEADS
#define NPAD 656      // 41 * 16

typedef short bf16x8 __attribute__((ext_vector_type(8)));
typedef float floatx4 __attribute__((ext_vector_type(4)));

__device__ __forceinline__ float siluf(float x) {
    return x / (1.f + expf(-x));
}
__device__ __forceinline__ float bf2f(unsigned short h) {
    unsigned int u = ((unsigned int)h) << 16;
    return __builtin_bit_cast(float, u);
}
__device__ __forceinline__ unsigned short f2bf(float f) {
    __hip_bfloat16 b = __float2bfloat16(f);
    return __builtin_bit_cast(unsigned short, b);
}
__device__ __forceinline__ void unpack8(bf16x8 v, float* o) {
    #pragma unroll
    for (int j = 0; j < 8; ++j) o[j] = bf2f((unsigned short)v[j]);
}
// async global->LDS, 16B per lane; LDS dest = wave-uniform base + lane*16
__device__ __forceinline__ void gl_lds16(const unsigned short* g, unsigned short* l) {
    __builtin_amdgcn_global_load_lds(
        (const __attribute__((address_space(1))) unsigned int*)g,
        (__attribute__((address_space(3))) unsigned int*)l, 16, 0, 0);
}

// ---------------------------------------------------------------------------
// Merged prep: all weight transposes+casts (incl. big MLP weight).
// blocks 0..655     : st/ex Win -> winT (656x128)
// blocks 656..911   : st/ex Wout -> woutT (128x256)
// blocks 912..1423  : 8 attn 128x128 mats -> attnWT
// blocks 1424..3471 : mlp_W fp32[2048][1024] -> bf16 Wt[1024][2048]
// ---------------------------------------------------------------------------
__global__ __launch_bounds__(256) void prep_weights(
    const float* __restrict__ st_Win, const float* __restrict__ ex_Win,
    const float* __restrict__ st_Wout, const float* __restrict__ ex_Wout,
    const float* __restrict__ cs_Wq, const float* __restrict__ cs_Wk,
    const float* __restrict__ cs_Wv, const float* __restrict__ cs_Wo,
    const float* __restrict__ cx_Wq, const float* __restrict__ cx_Wk,
    const float* __restrict__ cx_Wv, const float* __restrict__ cx_Wo,
    const float* __restrict__ mlp_W,
    unsigned short* __restrict__ winT_st, unsigned short* __restrict__ winT_ex,
    unsigned short* __restrict__ woutT_st, unsigned short* __restrict__ woutT_ex,
    unsigned short* __restrict__ attnWT, unsigned short* __restrict__ mlpWt)
{
    __shared__ float tile[32][33];
    int blk = blockIdx.x;
    if (blk < 656) {
        const float* src = blk < 328 ? st_Win : ex_Win;
        unsigned short* dst = blk < 328 ? winT_st : winT_ex;
        int idx = (blk % 328) * 256 + threadIdx.x;
        if (idx >= NPAD * 128) return;
        int n = idx / 128, k = idx % 128;
        float v = (n < DINPROJ) ? src[k * DINPROJ + n] : 0.f;
        dst[idx] = f2bf(v);
    } else if (blk < 912) {
        const float* src = blk < 784 ? st_Wout : ex_Wout;
        unsigned short* dst = blk < 784 ? woutT_st : woutT_ex;
        int idx = ((blk - 656) % 128) * 256 + threadIdx.x;
        int n = idx / 256, k = idx % 256;   // dst [128][256]
        dst[idx] = f2bf(src[k * 128 + n]);
    } else if (blk < 1424) {
        int b2 = blk - 912;
        int mat = b2 >> 6;
        const float* src = mat == 0 ? cs_Wq : mat == 1 ? cs_Wk : mat == 2 ? cs_Wv :
                           mat == 3 ? cs_Wo : mat == 4 ? cx_Wq : mat == 5 ? cx_Wk :
                           mat == 6 ? cx_Wv : cx_Wo;
        int e = (b2 & 63) * 256 + threadIdx.x;
        int n = e >> 7, k = e & 127;
        attnWT[mat * 16384 + n * 128 + k] = f2bf(src[k * 128 + n]);
    } else {
        int b2 = blk - 1424;                 // 2048 blocks: 32 n-tiles x 64 k-tiles
        int n0 = (b2 & 31) * 32, k0 = (b2 >> 5) * 32;
        const int tid = threadIdx.x;
        const int c = tid & 31, r0 = tid >> 5;
        for (int rr = r0; rr < 32; rr += 8)
            tile[rr][c] = mlp_W[(size_t)(k0 + rr) * 1024 + n0 + c];
        __syncthreads();
        for (int rr = r0; rr < 32; rr += 8)
            mlpWt[(size_t)(n0 + rr) * 2048 + k0 + c] = f2bf(tile[c][rr]);
    }
}

// ---------------------------------------------------------------------------
// Dual Mamba2 (unchanged from R5).
// ---------------------------------------------------------------------------
#define LDK 136
#define LDZ 648
#define LDY 264
__global__ __launch_bounds__(256, 4) void mamba_dual(
    const float* __restrict__ u_ex, const float* __restrict__ u_st,
    const unsigned short* __restrict__ WinT_ex, const unsigned short* __restrict__ WinT_st,
    const float* __restrict__ convw_ex, const float* __restrict__ convw_st,
    const float* __restrict__ convb_ex, const float* __restrict__ convb_st,
    const float* __restrict__ dtb_ex, const float* __restrict__ dtb_st,
    const float* __restrict__ Alog_ex, const float* __restrict__ Alog_st,
    const float* __restrict__ Dp_ex, const float* __restrict__ Dp_st,
    const float* __restrict__ normw_ex, const float* __restrict__ normw_st,
    const unsigned short* __restrict__ WoutT_ex, const unsigned short* __restrict__ WoutT_st,
    unsigned short* __restrict__ out_ex, unsigned short* __restrict__ out_st)
{
    const int which = blockIdx.x >> 10;
    const float* u = which ? u_st : u_ex;
    const unsigned short* WinT = which ? WinT_st : WinT_ex;
    const float* convw = which ? convw_st : convw_ex;
    const float* convb = which ? convb_st : convb_ex;
    const float* dtb = which ? dtb_st : dtb_ex;
    const float* Alog = which ? Alog_st : Alog_ex;
    const float* Dp = which ? Dp_st : Dp_ex;
    const float* normw = which ? normw_st : normw_ex;
    const unsigned short* WoutT = which ? WoutT_st : WoutT_ex;
    unsigned short* outf = which ? out_st : out_ex;

    const int tid = threadIdx.x;
    const int lane = tid & 63;
    const int wave = tid >> 6;
    const int l15 = lane & 15;
    const int q8 = (lane >> 4) * 8;
    const int row0 = (lane >> 4) * 4;
    const int grow0 = (blockIdx.x & 1023) * 16;

    __shared__ __align__(16) unsigned short uA[16 * LDK];
    __shared__ __align__(16) unsigned short zx[16 * LDZ];
    __shared__ __align__(16) unsigned short yb[16 * LDY];
    __shared__ float dtraw[16][8];
    __shared__ float dtv[2][8][8];
    __shared__ float cum[2][8][8];
    __shared__ float Gm[2][8][8];
    __shared__ float red[16][32];
    __shared__ float rstd[16];
    float* coefp = (float*)uA;

    for (int i = tid; i < 512; i += 256) {
        int r = i >> 5, k4 = (i & 31) * 4;
        float4 v = *(const float4*)(u + (size_t)(grow0 + r) * DMODEL + k4);
        ushort4 h;
        h.x = f2bf(v.x); h.y = f2bf(v.y); h.z = f2bf(v.z); h.w = f2bf(v.w);
        *(ushort4*)(uA + r * LDK + k4) = h;
    }
    __syncthreads();

    {
        bf16x8 af[4];
        #pragma unroll
        for (int kk = 0; kk < 4; ++kk)
            af[kk] = *(const bf16x8*)(uA + l15 * LDK + kk * 32 + q8);
        for (int nt = wave; nt < 41; nt += 4) {
            floatx4 acc = {0.f, 0.f, 0.f, 0.f};
            const unsigned short* bp = WinT + (size_t)(nt * 16 + l15) * 128 + q8;
            #pragma unroll
            for (int kk = 0; kk < 4; ++kk) {
                bf16x8 bf = *(const bf16x8*)(bp + kk * 32);
                acc = __builtin_amdgcn_mfma_f32_16x16x32_bf16(af[kk], bf, acc, 0, 0, 0);
            }
            if (nt == 40) {
                if (l15 < 8) {
                    #pragma unroll
                    for (int r = 0; r < 4; ++r)
                        dtraw[row0 + r][l15] = acc[r];
                }
            } else {
                #pragma unroll
                for (int r = 0; r < 4; ++r)
                    zx[(row0 + r) * LDZ + nt * 16 + l15] = f2bf(acc[r]);
            }
        }
    }
    __syncthreads();

    float cv[3][8];
    {
        #pragma unroll
        for (int it = 0; it < 3; ++it) {
            int i = tid + it * 256;
            int r = i / 48, g = i % 48;
            int c0 = g * 8;
            int l = r & 7, bloc = r >> 3;
            float s[8];
            float4 cb0 = *(const float4*)(convb + c0);
            float4 cb1 = *(const float4*)(convb + c0 + 4);
            s[0] = cb0.x; s[1] = cb0.y; s[2] = cb0.z; s[3] = cb0.w;
            s[4] = cb1.x; s[5] = cb1.y; s[6] = cb1.z; s[7] = cb1.w;
            #pragma unroll
            for (int k = 0; k < DCONV; ++k) {
                int lp = l + k - (DCONV - 1);
                if (lp >= 0) {
                    bf16x8 v = *(const bf16x8*)(zx + (bloc * 8 + lp) * LDZ + 256 + c0);
                    float vf[8];
                    unpack8(v, vf);
                    float4 w0 = *(const float4*)(convw + k * DCONVCH + c0);
                    float4 w1 = *(const float4*)(convw + k * DCONVCH + c0 + 4);
                    s[0] += vf[0] * w0.x; s[1] += vf[1] * w0.y;
                    s[2] += vf[2] * w0.z; s[3] += vf[3] * w0.w;
                    s[4] += vf[4] * w1.x; s[5] += vf[5] * w1.y;
                    s[6] += vf[6] * w1.z; s[7] += vf[7] * w1.w;
                }
            }
            #pragma unroll
            for (int j = 0; j < 8; ++j) cv[it][j] = siluf(s[j]);
        }
        if (tid < 128) {
            int r = tid >> 3, h = tid & 7;
            float v = dtraw[r][h] + dtb[h];
            dtv[r >> 3][r & 7][h] = (v > 20.f) ? v : log1pf(expf(v));
        }
    }
    __syncthreads();
    {
        #pragma unroll
        for (int it = 0; it < 3; ++it) {
            int i = tid + it * 256;
            int r = i / 48, c0 = (i % 48) * 8;
            bf16x8 o;
            #pragma unroll
            for (int j = 0; j < 8; ++j) o[j] = (short)f2bf(cv[it][j]);
            *(bf16x8*)(zx + r * LDZ + 256 + c0) = o;
        }
    }
    __syncthreads();

    if (tid < 128) {
        int bloc = tid >> 6, t = (tid >> 3) & 7, s = tid & 7;
        float a = 0.f;
        #pragma unroll
        for (int n = 0; n < DSTATE; n += 8) {
            bf16x8 bv = *(const bf16x8*)(zx + (bloc * 8 + s) * LDZ + 512 + n);
            bf16x8 cvv = *(const bf16x8*)(zx + (bloc * 8 + t) * LDZ + 576 + n);
            float bf_[8], cf_[8];
            unpack8(bv, bf_); unpack8(cvv, cf_);
            #pragma unroll
            for (int j = 0; j < 8; ++j) a += bf_[j] * cf_[j];
        }
        Gm[bloc][t][s] = a;
    } else if (tid < 144) {
        int j = tid - 128;
        int bloc = j >> 3, h = j & 7;
        float c = 0.f;
        for (int l = 0; l < L_SEQ; ++l) { c += dtv[bloc][l][h]; cum[bloc][l][h] = c; }
    }
    __syncthreads();

    for (int i = tid; i < 1024; i += 256) {
        int bloc = i >> 9, t = (i >> 6) & 7, s = (i >> 3) & 7, h = i & 7;
        float A = -expf(Alog[h]);
        coefp[i] = (s <= t)
            ? Gm[bloc][t][s] * expf(A * (cum[bloc][t][h] - cum[bloc][s][h])) * dtv[bloc][s][h]
            : 0.f;
    }
    __syncthreads();

    {
        #pragma unroll
        for (int it = 0; it < 2; ++it) {
            int i = tid + it * 256;
            int r = i >> 5, g = i & 31;
            int c0 = g * 8, h = g >> 2;
            int bloc = r >> 3, t = r & 7;
            float acc[8];
            {
                bf16x8 xv = *(const bf16x8*)(zx + r * LDZ + 256 + c0);
                float xf[8]; unpack8(xv, xf);
                float d = Dp[h];
                #pragma unroll
                for (int j = 0; j < 8; ++j) acc[j] = d * xf[j];
            }
            for (int s = 0; s <= t; ++s) {
                float cf = coefp[((bloc * 8 + t) * 8 + s) * 8 + h];
                bf16x8 xv = *(const bf16x8*)(zx + (bloc * 8 + s) * LDZ + 256 + c0);
                float xf[8]; unpack8(xv, xf);
                #pragma unroll
                for (int j = 0; j < 8; ++j) acc[j] += cf * xf[j];
            }
            bf16x8 zv = *(const bf16x8*)(zx + r * LDZ + c0);
            float zf[8]; unpack8(zv, zf);
            float p = 0.f;
            bf16x8 o;
            #pragma unroll
            for (int j = 0; j < 8; ++j) {
                float y = acc[j] * siluf(zf[j]);
                p += y * y;
                o[j] = (short)f2bf(y);
            }
            *(bf16x8*)(yb + r * LDY + c0) = o;
            red[r][g] = p;
        }
    }
    __syncthreads();
    if (tid < 16) {
        float s = 0.f;
        #pragma unroll
        for (int j = 0; j < 32; ++j) s += red[tid][j];
        rstd[tid] = rsqrtf(s / (float)DINNER + 1e-5f);
    }
    __syncthreads();
    {
        #pragma unroll
        for (int it = 0; it < 2; ++it) {
            int i = tid + it * 256;
            int r = i >> 5, c0 = (i & 31) * 8;
            bf16x8 v = *(const bf16x8*)(yb + r * LDY + c0);
            float vf[8]; unpack8(v, vf);
            float4 w0 = *(const float4*)(normw + c0);
            float4 w1 = *(const float4*)(normw + c0 + 4);
            float rs = rstd[r];
            bf16x8 o;
            o[0] = (short)f2bf(vf[0] * rs * w0.x); o[1] = (short)f2bf(vf[1] * rs * w0.y);
            o[2] = (short)f2bf(vf[2] * rs * w0.z); o[3] = (short)f2bf(vf[3] * rs * w0.w);
            o[4] = (short)f2bf(vf[4] * rs * w1.x); o[5] = (short)f2bf(vf[5] * rs * w1.y);
            o[6] = (short)f2bf(vf[6] * rs * w1.z); o[7] = (short)f2bf(vf[7] * rs * w1.w);
            *(bf16x8*)(yb + r * LDY + c0) = o;
        }
    }
    __syncthreads();

    {
        bf16x8 af[8];
        #pragma unroll
        for (int kk = 0; kk < 8; ++kk)
            af[kk] = *(const bf16x8*)(yb + l15 * LDY + kk * 32 + q8);
        #pragma unroll
        for (int ni = 0; ni < 2; ++ni) {
            int nt = wave * 2 + ni;
            floatx4 acc = {0.f, 0.f, 0.f, 0.f};
            const unsigned short* bp = WoutT + (size_t)(nt * 16 + l15) * 256 + q8;
            #pragma unroll
            for (int kk = 0; kk < 8; ++kk) {
                bf16x8 bf = *(const bf16x8*)(bp + kk * 32);
                acc = __builtin_amdgcn_mfma_f32_16x16x32_bf16(af[kk], bf, acc, 0, 0, 0);
            }
            #pragma unroll
            for (int r = 0; r < 4; ++r)
                outf[(size_t)(grow0 + row0 + r) * DMODEL + nt * 16 + l15] = f2bf(acc[r]);
        }
    }
}

// ---------------------------------------------------------------------------
// Cross-attentions, 4 batches per block (M=32), grid B/4 = 512.
// kv dim per pass = 32 rows (4 batches x 8); P is block-diagonal 8x8.
// ---------------------------------------------------------------------------
#define ASTR 136
#define VSTR 40
#define PSTR 40
__global__ __launch_bounds__(256, 2) void attn_kernel(
    const unsigned short* __restrict__ st_f,
    const unsigned short* __restrict__ exp_f,
    const unsigned short* __restrict__ WT,
    const float* __restrict__ cs_bq, const float* __restrict__ cs_bk,
    const float* __restrict__ cs_bv, const float* __restrict__ cs_bo,
    const float* __restrict__ cx_bq, const float* __restrict__ cx_bk,
    const float* __restrict__ cx_bv, const float* __restrict__ cx_bo,
    __hip_bfloat16* __restrict__ x)
{
    const int tid = threadIdx.x;
    const int lane = tid & 63, wave = tid >> 6;
    const int l15 = lane & 15;
    const int q8 = (lane >> 4) * 8;
    const int row0 = (lane >> 4) * 4;
    const int grow0 = blockIdx.x * 32;
    const int b0 = blockIdx.x * 4;
    const float scale = 0.08838834764831845f;

    __shared__ __align__(16) unsigned short stf[32 * ASTR];
    __shared__ __align__(16) unsigned short exf[32 * ASTR];
    __shared__ __align__(16) unsigned short Qs[32 * ASTR];
    __shared__ __align__(16) unsigned short Ks[32 * ASTR];
    __shared__ __align__(16) unsigned short attv[32 * ASTR];
    __shared__ __align__(16) unsigned short Vt[128 * VSTR];  // [chan][kvrow 0..31]
    __shared__ __align__(16) unsigned short P[32 * PSTR];
    __shared__ float Ss[32][33];

    #pragma unroll
    for (int it = 0; it < 2; ++it) {
        int i = tid + it * 256;
        int r = i >> 4, c8 = (i & 15) * 8;
        *(uint4*)(stf + r * ASTR + c8) = *(const uint4*)(st_f + (size_t)(grow0 + r) * 128 + c8);
        *(uint4*)(exf + r * ASTR + c8) = *(const uint4*)(exp_f + (size_t)(grow0 + r) * 128 + c8);
    }
    __syncthreads();

    #pragma unroll
    for (int pass = 0; pass < 2; ++pass) {
        const unsigned short* qsrc = pass ? exf : stf;
        const unsigned short* kvsrc = pass ? stf : exf;
        const unsigned short* Wq = WT + (size_t)pass * 4 * 16384;
        const unsigned short* Wk = Wq + 16384;
        const unsigned short* Wv = Wq + 32768;
        const unsigned short* Wo = Wq + 49152;
        const float* bq = pass ? cx_bq : cs_bq;
        const float* bk = pass ? cx_bk : cs_bk;
        const float* bv = pass ? cx_bv : cs_bv;
        const float* bo = pass ? cx_bo : cs_bo;

        // --- Q/K/V projections (2 m-tiles x 2 n-tiles per wave) ---
        {
            bf16x8 aq[2][4], akv[2][4];
            #pragma unroll
            for (int mt = 0; mt < 2; ++mt)
                #pragma unroll
                for (int kk = 0; kk < 4; ++kk) {
                    aq[mt][kk]  = *(const bf16x8*)(qsrc  + (mt * 16 + l15) * ASTR + kk * 32 + q8);
                    akv[mt][kk] = *(const bf16x8*)(kvsrc + (mt * 16 + l15) * ASTR + kk * 32 + q8);
                }
            #pragma unroll
            for (int ni = 0; ni < 2; ++ni) {
                int nc = (wave * 2 + ni) * 16 + l15;
                floatx4 aq0 = {0,0,0,0}, aq1 = {0,0,0,0};
                floatx4 ak0 = {0,0,0,0}, ak1 = {0,0,0,0};
                floatx4 av0 = {0,0,0,0}, av1 = {0,0,0,0};
                #pragma unroll
                for (int kk = 0; kk < 4; ++kk) {
                    bf16x8 wqf = *(const bf16x8*)(Wq + (size_t)nc * 128 + kk * 32 + q8);
                    bf16x8 wkf = *(const bf16x8*)(Wk + (size_t)nc * 128 + kk * 32 + q8);
                    bf16x8 wvf = *(const bf16x8*)(Wv + (size_t)nc * 128 + kk * 32 + q8);
                    aq0 = __builtin_amdgcn_mfma_f32_16x16x32_bf16(aq[0][kk],  wqf, aq0, 0, 0, 0);
                    aq1 = __builtin_amdgcn_mfma_f32_16x16x32_bf16(aq[1][kk],  wqf, aq1, 0, 0, 0);
                    ak0 = __builtin_amdgcn_mfma_f32_16x16x32_bf16(akv[0][kk], wkf, ak0, 0, 0, 0);
                    ak1 = __builtin_amdgcn_mfma_f32_16x16x32_bf16(akv[1][kk], wkf, ak1, 0, 0, 0);
                    av0 = __builtin_amdgcn_mfma_f32_16x16x32_bf16(akv[0][kk], wvf, av0, 0, 0, 0);
                    av1 = __builtin_amdgcn_mfma_f32_16x16x32_bf16(akv[1][kk], wvf, av1, 0, 0, 0);
                }
                float bqv = bq[nc], bkv = bk[nc], bvv = bv[nc];
                #pragma unroll
                for (int r = 0; r < 4; ++r) {
                    Qs[(row0 + r) * ASTR + nc]      = f2bf(aq0[r] + bqv);
                    Qs[(16 + row0 + r) * ASTR + nc] = f2bf(aq1[r] + bqv);
                    Ks[(row0 + r) * ASTR + nc]      = f2bf(ak0[r] + bkv);
                    Ks[(16 + row0 + r) * ASTR + nc] = f2bf(ak1[r] + bkv);
                    Vt[nc * VSTR + row0 + r]        = f2bf(av0[r] + bvv);
                    Vt[nc * VSTR + 16 + row0 + r]   = f2bf(av1[r] + bvv);
                }
            }
        }
        __syncthreads();

        // --- scores: S(32x32) = Q @ K^T; wave w does tile (w>>1, w&1) ---
        {
            int mtS = wave >> 1, ntS = wave & 1;
            floatx4 s = {0,0,0,0};
            #pragma unroll
            for (int kk = 0; kk < 4; ++kk) {
                bf16x8 a = *(const bf16x8*)(Qs + (mtS * 16 + l15) * ASTR + kk * 32 + q8);
                bf16x8 b = *(const bf16x8*)(Ks + (ntS * 16 + l15) * ASTR + kk * 32 + q8);
                s = __builtin_amdgcn_mfma_f32_16x16x32_bf16(a, b, s, 0, 0, 0);
            }
            #pragma unroll
            for (int r = 0; r < 4; ++r)
                Ss[mtS * 16 + row0 + r][ntS * 16 + l15] = s[r];
        }
        __syncthreads();

        // --- softmax per q-row over its batch's 8 kv cols; build P ---
        if (tid < 32) {
            int r = tid, c0 = (r >> 3) * 8;
            float v[8], mx = -1e30f;
            #pragma unroll
            for (int c = 0; c < 8; ++c) {
                v[c] = Ss[r][c0 + c] * scale;
                mx = fmaxf(mx, v[c]);
            }
            float sum = 0.f;
            #pragma unroll
            for (int c = 0; c < 8; ++c) { v[c] = expf(v[c] - mx); sum += v[c]; }
            float inv = 1.f / sum;
            #pragma unroll
            for (int c = 0; c < 32; ++c) {
                float pv = (c >= c0 && c < c0 + 8) ? v[c - c0] * inv : 0.f;
                P[r * PSTR + c] = f2bf(pv);
            }
        }
        __syncthreads();

        // --- O = P(32x32) @ V(32x128): per wave 2 n-tiles x 2 m-tiles ---
        {
            #pragma unroll
            for (int ni = 0; ni < 2; ++ni) {
                int nc = (wave * 2 + ni) * 16 + l15;
                bf16x8 bv_ = *(const bf16x8*)(Vt + nc * VSTR + q8);
                #pragma unroll
                for (int mt = 0; mt < 2; ++mt) {
                    bf16x8 ap = *(const bf16x8*)(P + (mt * 16 + l15) * PSTR + q8);
                    floatx4 o = {0,0,0,0};
                    o = __builtin_amdgcn_mfma_f32_16x16x32_bf16(ap, bv_, o, 0, 0, 0);
                    #pragma unroll
                    for (int r = 0; r < 4; ++r)
                        attv[(mt * 16 + row0 + r) * ASTR + nc] = f2bf(o[r]);
                }
            }
        }
        __syncthreads();

        // --- Wo projection -> x ---
        {
            bf16x8 ao[2][4];
            #pragma unroll
            for (int mt = 0; mt < 2; ++mt)
                #pragma unroll
                for (int kk = 0; kk < 4; ++kk)
                    ao[mt][kk] = *(const bf16x8*)(attv + (mt * 16 + l15) * ASTR + kk * 32 + q8);
            #pragma unroll
            for (int ni = 0; ni < 2; ++ni) {
                int nc = (wave * 2 + ni) * 16 + l15;
                floatx4 a0 = {0,0,0,0}, a1 = {0,0,0,0};
                #pragma unroll
                for (int kk = 0; kk < 4; ++kk) {
                    bf16x8 wof = *(const bf16x8*)(Wo + (size_t)nc * 128 + kk * 32 + q8);
                    a0 = __builtin_amdgcn_mfma_f32_16x16x32_bf16(ao[0][kk], wof, a0, 0, 0, 0);
                    a1 = __builtin_amdgcn_mfma_f32_16x16x32_bf16(ao[1][kk], wof, a1, 0, 0, 0);
                }
                float bov = bo[nc];
                #pragma unroll
                for (int r = 0; r < 4; ++r) {
                    int rr0 = row0 + r;
                    int rr1 = 16 + row0 + r;
                    x[(size_t)(b0 + (rr0 >> 3)) * 2048 + (rr0 & 7) * 256 + pass * 128 + nc] =
                        __float2bfloat16(a0[r] + bov);
                    x[(size_t)(b0 + (rr1 >> 3)) * 2048 + (rr1 & 7) * 256 + pass * 128 + nc] =
                        __float2bfloat16(a1[r] + bov);
                }
            }
        }
        __syncthreads();
    }
}

// ---------------------------------------------------------------------------
// MLP via MFMA v2: 64x64 tile, BK=64, global_load_lds staging with XOR
// swizzle (chunk = r*8 + (c16 ^ (r&7)); 16B chunks). 512 blocks.
// ---------------------------------------------------------------------------
__global__ __launch_bounds__(256, 2) void mlp_mfma(
    const unsigned short* __restrict__ X,   // [2048][2048] bf16
    const unsigned short* __restrict__ Wt,  // [1024][2048] bf16
    const float* __restrict__ bias,
    float* __restrict__ out)                // [2048][1024]
{
    __shared__ __align__(16) unsigned short As[64 * 64];
    __shared__ __align__(16) unsigned short Bs[64 * 64];
    const int tid = threadIdx.x;
    const int wave = tid >> 6, lane = tid & 63;
    const int wm = (wave >> 1) * 32, wn = (wave & 1) * 32;
    const int bm = blockIdx.y * 64, bn = blockIdx.x * 64;
    const int l15 = lane & 15, q8 = (lane >> 4) * 8;

    // staging: thread handles chunks tid and tid+256 (512 chunks per tile)
    const int c0i = tid, c1i = tid + 256;
    const int r0s = c0i >> 3, c0s = ((c0i & 7) ^ (r0s & 7)) * 8;
    const int r1s = c1i >> 3, c1s = ((c1i & 7) ^ (r1s & 7)) * 8;
    const unsigned short* gA0 = X + (size_t)(bm + r0s) * 2048 + c0s;
    const unsigned short* gA1 = X + (size_t)(bm + r1s) * 2048 + c1s;
    const unsigned short* gB0 = Wt + (size_t)(bn + r0s) * 2048 + c0s;
    const unsigned short* gB1 = Wt + (size_t)(bn + r1s) * 2048 + c1s;
    unsigned short* lA0 = As + c0i * 8;
    unsigned short* lA1 = As + c1i * 8;
    unsigned short* lB0 = Bs + c0i * 8;
    unsigned short* lB1 = Bs + c1i * 8;

    floatx4 acc[2][2];
    #pragma unroll
    for (int i = 0; i < 2; ++i)
        #pragma unroll
        for (int j = 0; j < 2; ++j) acc[i][j] = (floatx4){0.f, 0.f, 0.f, 0.f};

    const int ra0 = wm + l15, ra1 = wm + 16 + l15;
    const int rb0 = wn + l15, rb1 = wn + 16 + l15;

    for (int k0 = 0; k0 < 2048; k0 += 64) {
        __syncthreads();          // previous iteration's ds_reads done
        gl_lds16(gA0 + k0, lA0);
        gl_lds16(gA1 + k0, lA1);
        gl_lds16(gB0 + k0, lB0);
        gl_lds16(gB1 + k0, lB1);
        __syncthreads();          // drains vmcnt (loads landed in LDS)
        #pragma unroll
        for (int ks = 0; ks < 2; ++ks) {
            int xx = ks * 4 + (q8 >> 3);
            bf16x8 a0 = *(const bf16x8*)(As + (ra0 * 8 + (xx ^ (ra0 & 7))) * 8);
            bf16x8 a1 = *(const bf16x8*)(As + (ra1 * 8 + (xx ^ (ra1 & 7))) * 8);
            bf16x8 b0 = *(const bf16x8*)(Bs + (rb0 * 8 + (xx ^ (rb0 & 7))) * 8);
            bf16x8 b1 = *(const bf16x8*)(Bs + (rb1 * 8 + (xx ^ (rb1 & 7))) * 8);
            acc[0][0] = __builtin_amdgcn_mfma_f32_16x16x32_bf16(a0, b0, acc[0][0], 0, 0, 0);
            acc[0][1] = __builtin_amdgcn_mfma_f32_16x16x32_bf16(a0, b1, acc[0][1], 0, 0, 0);
            acc[1][0] = __builtin_amdgcn_mfma_f32_16x16x32_bf16(a1, b0, acc[1][0], 0, 0, 0);
            acc[1][1] = __builtin_amdgcn_mfma_f32_16x16x32_bf16(a1, b1, acc[1][1], 0, 0, 0);
        }
    }

    const int row0 = (lane >> 4) * 4;
    #pragma unroll
    for (int j = 0; j < 2; ++j) {
        int col = bn + wn + j * 16 + l15;
        float bv = bias[col];
        #pragma unroll
        for (int r = 0; r < 4; ++r) {
            out[(size_t)(bm + wm + row0 + r) * 1024 + col] = acc[0][j][r] + bv;
            out[(size_t)(bm + wm + 16 + row0 + r) * 1024 + col] = acc[1][j][r] + bv;
        }
    }
}

extern "C" void kernel_launch(void* const* d_in, const int* in_sizes, int n_in,
                              void* d_out, int out_size, void* d_ws, size_t ws_size,
                              hipStream_t stream) {
    const float* st_feature = (const float*)d_in[0];
    const float* exp_feature = (const float*)d_in[1];
    const float* st_Win = (const float*)d_in[2];
    const float* st_convw = (const float*)d_in[3];
    const float* st_convb = (const float*)d_in[4];
    const float* st_dtb = (const float*)d_in[5];
    const float* st_Alog = (const float*)d_in[6];
    const float* st_D = (const float*)d_in[7];
    const float* st_normw = (const float*)d_in[8];
    const float* st_Wout = (const float*)d_in[9];
    const float* ex_Win = (const float*)d_in[10];
    const float* ex_convw = (const float*)d_in[11];
    const float* ex_convb = (const float*)d_in[12];
    const float* ex_dtb = (const float*)d_in[13];
    const float* ex_Alog = (const float*)d_in[14];
    const float* ex_D = (const float*)d_in[15];
    const float* ex_normw = (const float*)d_in[16];
    const float* ex_Wout = (const float*)d_in[17];
    const float* cx_Wq = (const float*)d_in[18]; const float* cx_bq = (const float*)d_in[19];
    const float* cx_Wk = (const float*)d_in[20]; const float* cx_bk = (const float*)d_in[21];
    const float* cx_Wv = (const float*)d_in[22]; const float* cx_bv = (const float*)d_in[23];
    const float* cx_Wo = (const float*)d_in[24]; const float* cx_bo = (const float*)d_in[25];
    const float* cs_Wq = (const float*)d_in[26]; const float* cs_bq = (const float*)d_in[27];
    const float* cs_Wk = (const float*)d_in[28]; const float* cs_bk = (const float*)d_in[29];
    const float* cs_Wv = (const float*)d_in[30]; const float* cs_bv = (const float*)d_in[31];
    const float* cs_Wo = (const float*)d_in[32]; const float* cs_bo = (const float*)d_in[33];
    const float* mlp_W = (const float*)d_in[34];
    const float* mlp_b = (const float*)d_in[35];

    unsigned short* wsu = (unsigned short*)d_ws;
    unsigned short* st_fb  = wsu;
    unsigned short* exp_fb = st_fb + (size_t)B_SZ * L_SEQ * DMODEL;
    unsigned short* xbuf   = exp_fb + (size_t)B_SZ * L_SEQ * DMODEL;
    unsigned short* wtbuf  = xbuf + (size_t)2048 * 2048;
    unsigned short* winT_st = wtbuf + (size_t)1024 * 2048;
    unsigned short* winT_ex = winT_st + (size_t)NPAD * 128;
    unsigned short* woutT_st = winT_ex + (size_t)NPAD * 128;
    unsigned short* woutT_ex = woutT_st + (size_t)128 * 256;
    unsigned short* attnWT  = woutT_ex + (size_t)128 * 256;

    prep_weights<<<3472, 256, 0, stream>>>(
        st_Win, ex_Win, st_Wout, ex_Wout,
        cs_Wq, cs_Wk, cs_Wv, cs_Wo, cx_Wq, cx_Wk, cx_Wv, cx_Wo, mlp_W,
        winT_st, winT_ex, woutT_st, woutT_ex, attnWT, wtbuf);
    mamba_dual<<<2048, 256, 0, stream>>>(
        exp_feature, st_feature, winT_ex, winT_st,
        ex_convw, st_convw, ex_convb, st_convb,
        ex_dtb, st_dtb, ex_Alog, st_Alog, ex_D, st_D,
        ex_normw, st_normw, woutT_ex, woutT_st,
        exp_fb, st_fb);
    attn_kernel<<<B_SZ / 4, 256, 0, stream>>>(st_fb, exp_fb, attnWT,
                                              cs_bq, cs_bk, cs_bv, cs_bo,
                                              cx_bq, cx_bk, cx_bv, cx_bo,
                                              (__hip_bfloat16*)xbuf);
    {
        dim3 g(1024 / 64, 2048 / 64);
        mlp_mfma<<<g, 256, 0, stream>>>(xbuf, wtbuf, mlp_b, (float*)d_out);
    }
}